// Round 10
// baseline (256.666 us; speedup 1.0000x reference)
//
// R15: attention reverted to R13 exactly (238.7us proven; R14's (256,3)+diet
// caused spills, reverted). New: gemm_out K-split x2 -> 160 blocks (was 80 =
// 31% CU util): same 384x192 8-phase template over a (kbase,klen) range,
// f32 atomicAdd accumulation into hipMemsetAsync-zeroed out (capture-legal,
// idempotent), bias added by ks==0 blocks only. qkv instantiates (0,1536) =
// byte-identical schedule.
#include <hip/hip_runtime.h>

#define LSEQ 3683
#define LPAD 3840
#define DIMSZ 1536
#define NHEAD 12
#define HEADD 128
#define SM_SCALE 0.088388347648318447f   // 1/sqrt(128)

typedef unsigned short u16;
typedef unsigned int u32;
typedef __bf16 bf16x8 __attribute__((ext_vector_type(8)));
typedef float f32x4 __attribute__((ext_vector_type(4)));

__device__ __forceinline__ u16 f2b(float f) {
  u32 u = __float_as_uint(f);
  u += 0x7FFFu + ((u >> 16) & 1u);   // RNE
  return (u16)(u >> 16);
}
__device__ __forceinline__ float b2f(u16 s) {
  return __uint_as_float(((u32)s) << 16);
}
__device__ __forceinline__ int imax(int a, int b) { return a > b ? a : b; }

// async global->LDS, 16B per lane; lds base must be wave-uniform.
__device__ __forceinline__ void gl_lds16(const u16* g, u16* l) {
  __builtin_amdgcn_global_load_lds((const __attribute__((address_space(1))) u32*)g,
                                   (__attribute__((address_space(3))) u32*)l,
                                   16, 0, 0);
}

// bijective XCD-chunk swizzle (m204): round-robin orig -> contiguous chunks.
__device__ __forceinline__ int xcd_swz(int orig, int nwg) {
  int q = nwg >> 3, r = nwg & 7;
  int x = orig & 7, l = orig >> 3;
  return (x < r ? x * (q + 1) : r * (q + 1) + (x - r) * q) + l;
}

// ---------------- fused prep: x f32->bf16 pad + W transposes ----------------
#define CONV_BLOCKS 5760   // (LPAD*DIMSZ/4)/256
__global__ void prep_kernel(const float* __restrict__ x, u16* __restrict__ xb,
                            const float* __restrict__ W0, const float* __restrict__ W1,
                            const float* __restrict__ W2, const float* __restrict__ W3,
                            u16* __restrict__ Wt) {
  __shared__ float tile[32][33];
  int bx = blockIdx.x;
  if (bx < CONV_BLOCKS) {
    long idx = (long)bx * blockDim.x + threadIdx.x;
    long base = idx * 4;
    if (base >= (long)LPAD * DIMSZ) return;
    float4 v;
    if (base < (long)LSEQ * DIMSZ) v = *(const float4*)(x + base);
    else v = make_float4(0.f, 0.f, 0.f, 0.f);
    ushort4 o;
    o.x = f2b(v.x); o.y = f2b(v.y); o.z = f2b(v.z); o.w = f2b(v.w);
    *(ushort4*)(xb + base) = o;
  } else {
    int i = bx - CONV_BLOCKS;
    int z = i / 2304;               // 48*48 per matrix
    int r = i % 2304;
    int bxx = r % 48, byy = r / 48;
    const float* W = (z == 0) ? W0 : (z == 1) ? W1 : (z == 2) ? W2 : W3;
    u16* dst = Wt + (size_t)z * DIMSZ * DIMSZ;
    int k0 = bxx * 32, n0 = byy * 32;
    int tx = threadIdx.x & 31, ty = threadIdx.x >> 5;
    #pragma unroll
    for (int q = 0; q < 4; q++) {
      int k = k0 + ty + q * 8;
      tile[ty + q * 8][tx] = W[(size_t)k * DIMSZ + n0 + tx];
    }
    __syncthreads();
    #pragma unroll
    for (int q = 0; q < 4; q++) {
      int n = n0 + ty + q * 8;
      dst[(size_t)n * DIMSZ + k0 + tx] = f2b(tile[tx][ty + q * 8]);
    }
  }
}

// ================== 384x192 8-phase GEMM template ==================
#define BAR() __builtin_amdgcn_s_barrier()
#define LGK0() asm volatile("s_waitcnt lgkmcnt(0)" ::: "memory")
#define LGK8() asm volatile("s_waitcnt lgkmcnt(8)" ::: "memory")
#define VMC9() asm volatile("s_waitcnt vmcnt(9)" ::: "memory")
#define VMC6() asm volatile("s_waitcnt vmcnt(6)" ::: "memory")
#define VMC0() asm volatile("s_waitcnt vmcnt(0)" ::: "memory")
#define PRIO1() __builtin_amdgcn_s_setprio(1)
#define PRIO0() __builtin_amdgcn_s_setprio(0)

// one 64-row staging issue (512 threads x 16B = 64 rows of 128B)
#define STG_A(buf, q, kt) \
  gl_lds16(gA + (size_t)((q) * 64) * DIMSZ + (kt), &Asg[buf][((q) * 64 + w * 8) * 64]);
#define STG_B(buf, q, kt) \
  gl_lds16(gB + (size_t)((q) * 64) * DIMSZ + (kt), &Bsg[buf][((q) * 64 + w * 8) * 64]);

// ds-read register subtiles (swizzled offsets off0/off1); 6 ds_read_b128 each
#define LDA3(buf, mh) { \
  _Pragma("unroll") for (int mf = 0; mf < 3; mf++) { \
    int rb = (wm * 96 + (mh) * 48 + mf * 16) * 64; \
    Ar[mf * 2 + 0] = *(const bf16x8*)&Asg[buf][rb + off0]; \
    Ar[mf * 2 + 1] = *(const bf16x8*)&Asg[buf][rb + off1]; } }
#define LDB3(buf, nh) { \
  _Pragma("unroll") for (int nf = 0; nf < 3; nf++) { \
    int rb = (wn * 96 + (nh) * 48 + nf * 16) * 64; \
    Br[nh][nf * 2 + 0] = *(const bf16x8*)&Bsg[buf][rb + off0]; \
    Br[nh][nf * 2 + 1] = *(const bf16x8*)&Bsg[buf][rb + off1]; } }

// one C-quadrant (3x3 frags) x K=64: 18 MFMA
#define MFMAQ3(mh, nh) { \
  _Pragma("unroll") for (int mf = 0; mf < 3; mf++) \
    _Pragma("unroll") for (int nf = 0; nf < 3; nf++) { \
      acc[(mh)*3+mf][(nh)*3+nf] = __builtin_amdgcn_mfma_f32_16x16x32_bf16(Ar[mf*2+0], Br[nh][nf*2+0], acc[(mh)*3+mf][(nh)*3+nf], 0, 0, 0); \
      acc[(mh)*3+mf][(nh)*3+nf] = __builtin_amdgcn_mfma_f32_16x16x32_bf16(Ar[mf*2+1], Br[nh][nf*2+1], acc[(mh)*3+mf][(nh)*3+nf], 0, 0, 0); } }

// shared body over K range [kb, kb+klen): prologue staging + main loop + peel
#define GEMM384_BODY_K(kb, klen) \
  STG_B(0, 0, (kb)) STG_B(0, 1, (kb)) STG_B(0, 2, (kb)) \
  STG_A(0, 0, (kb)) STG_A(0, 1, (kb)) STG_A(0, 2, (kb)) \
  STG_A(0, 3, (kb)) STG_A(0, 4, (kb)) STG_A(0, 5, (kb)) \
  STG_B(1, 0, (kb) + 64) STG_B(1, 1, (kb) + 64) STG_B(1, 2, (kb) + 64) \
  STG_A(1, 0, (kb) + 64) STG_A(1, 1, (kb) + 64) STG_A(1, 2, (kb) + 64) \
  STG_A(1, 3, (kb) + 64) STG_A(1, 4, (kb) + 64) STG_A(1, 5, (kb) + 64) \
  VMC9(); \
  BAR(); \
  for (int i = 0; i < (klen) / 128 - 1; ++i) { \
    int kt2 = (kb) + (2 * i + 2) * 64; \
    int kt3 = (kb) + (2 * i + 3) * 64; \
    LDA3(0, 0) LDB3(0, 0) \
    LGK8(); BAR(); LGK0(); \
    PRIO1(); MFMAQ3(0, 0) PRIO0(); \
    BAR(); \
    LDB3(0, 1) \
    BAR(); LGK0(); \
    PRIO1(); MFMAQ3(0, 1) PRIO0(); \
    BAR(); \
    LDA3(0, 1) \
    STG_B(0, 0, kt2) STG_B(0, 1, kt2) STG_B(0, 2, kt2) \
    BAR(); LGK0(); \
    PRIO1(); MFMAQ3(1, 1) PRIO0(); \
    BAR(); \
    STG_A(0, 0, kt2) STG_A(0, 1, kt2) STG_A(0, 2, kt2) \
    VMC6(); BAR(); \
    PRIO1(); MFMAQ3(1, 0) PRIO0(); \
    BAR(); \
    LDA3(1, 0) LDB3(1, 0) \
    STG_A(0, 3, kt2) STG_A(0, 4, kt2) STG_A(0, 5, kt2) \
    LGK8(); BAR(); LGK0(); \
    PRIO1(); MFMAQ3(0, 0) PRIO0(); \
    BAR(); \
    LDB3(1, 1) \
    BAR(); LGK0(); \
    PRIO1(); MFMAQ3(0, 1) PRIO0(); \
    BAR(); \
    LDA3(1, 1) \
    STG_B(1, 0, kt3) STG_B(1, 1, kt3) STG_B(1, 2, kt3) \
    BAR(); LGK0(); \
    PRIO1(); MFMAQ3(1, 1) PRIO0(); \
    BAR(); \
    STG_A(1, 0, kt3) STG_A(1, 1, kt3) STG_A(1, 2, kt3) \
    STG_A(1, 3, kt3) STG_A(1, 4, kt3) STG_A(1, 5, kt3) \
    VMC9(); BAR(); \
    PRIO1(); MFMAQ3(1, 0) PRIO0(); \
    BAR(); \
  } \
  { \
    LDA3(0, 0) LDB3(0, 0) \
    LGK8(); BAR(); LGK0(); \
    PRIO1(); MFMAQ3(0, 0) PRIO0(); \
    BAR(); \
    LDB3(0, 1) \
    BAR(); LGK0(); \
    PRIO1(); MFMAQ3(0, 1) PRIO0(); \
    BAR(); \
    LDA3(0, 1) \
    BAR(); LGK0(); \
    PRIO1(); MFMAQ3(1, 1) PRIO0(); \
    BAR(); \
    VMC0(); BAR(); \
    PRIO1(); MFMAQ3(1, 0) PRIO0(); \
    BAR(); \
    LDA3(1, 0) LDB3(1, 0) \
    LGK8(); BAR(); LGK0(); \
    PRIO1(); MFMAQ3(0, 0) PRIO0(); \
    BAR(); \
    LDB3(1, 1) \
    BAR(); LGK0(); \
    PRIO1(); MFMAQ3(0, 1) PRIO0(); \
    BAR(); \
    LDA3(1, 1) \
    BAR(); LGK0(); \
    PRIO1(); MFMAQ3(1, 1) PRIO0(); \
    MFMAQ3(1, 0) \
  }

#define GEMM384_BODY() GEMM384_BODY_K(0, DIMSZ)

__launch_bounds__(512, 2)
__global__ void gemm_qkv384_kernel(const u16* __restrict__ A, const u16* __restrict__ Wt,
                                   const float* __restrict__ bq, const float* __restrict__ bk,
                                   const float* __restrict__ bv,
                                   u16* __restrict__ Qb, u16* __restrict__ Kb,
                                   u16* __restrict__ Vt) {
  __shared__ __align__(16) u16 Asg[2][384 * 64];
  __shared__ __align__(16) u16 Bsg[2][192 * 64];

  int wg = xcd_swz(blockIdx.x, 10 * 24);
  int nt = wg % 24;                    // 24 col tiles of 192 (8 per matrix)
  int m0 = (wg / 24) * 384;
  int which = nt >> 3;
  const float* bias = (which == 0) ? bq : (which == 1) ? bk : bv;

  int t = threadIdx.x;
  int lane = t & 63, w = t >> 6;       // 8 waves
  int c = lane & 15, g = lane >> 4;
  int wm = w >> 1, wn = w & 1;         // 4x2 wave grid; wave tile 96x96

  int srow = t >> 3;
  int schunk = ((t & 7) ^ (srow & 7)) * 8;
  const u16* gA = A + (size_t)(m0 + srow) * DIMSZ + schunk;
  const u16* gB = Wt + (size_t)(nt * 192 + srow) * DIMSZ + schunk;

  int off0 = c * 64 + ((g) ^ (c & 7)) * 8;
  int off1 = c * 64 + ((g + 4) ^ (c & 7)) * 8;

  f32x4 acc[6][6];
  f32x4 zero = {0.f, 0.f, 0.f, 0.f};
  #pragma unroll
  for (int am = 0; am < 6; am++)
    #pragma unroll
    for (int an = 0; an < 6; an++) acc[am][an] = zero;
  bf16x8 Ar[6];
  bf16x8 Br[2][6];

  GEMM384_BODY()

  // epilogue: bias add + write. Q/K row-major, V transposed (pack 4 rows).
  #pragma unroll
  for (int an = 0; an < 6; an++) {
    int ncol = (nt & 7) * 192 + wn * 96 + (an / 3) * 48 + (an % 3) * 16 + c;
    float bvv = bias[ncol];
    #pragma unroll
    for (int am = 0; am < 6; am++) {
      int rowb = m0 + wm * 96 + (am / 3) * 48 + (am % 3) * 16 + 4 * g;
      if (which == 2) {
        ushort4 pv;
        pv.x = f2b(acc[am][an][0] + bvv);
        pv.y = f2b(acc[am][an][1] + bvv);
        pv.z = f2b(acc[am][an][2] + bvv);
        pv.w = f2b(acc[am][an][3] + bvv);
        *(ushort4*)&Vt[(size_t)ncol * LPAD + rowb] = pv;
      } else {
        u16* P = (which == 1) ? Kb : Qb;
        #pragma unroll
        for (int r = 0; r < 4; r++)
          P[(size_t)(rowb + r) * DIMSZ + ncol] = f2b(acc[am][an][r] + bvv);
      }
    }
  }
}

// ------- final GEMM: out f32 += A bf16 @ Wo (+bias), K-split x2, atomicAdd -------
__launch_bounds__(512, 2)
__global__ void gemm_out384_kernel(const u16* __restrict__ A, const u16* __restrict__ Bt,
                                   const float* __restrict__ bias, float* __restrict__ outF) {
  __shared__ __align__(16) u16 Asg[2][384 * 64];
  __shared__ __align__(16) u16 Bsg[2][192 * 64];

  int wg = xcd_swz(blockIdx.x, 160);
  int nt = (wg % 16) >> 1;             // 8 col tiles of 192
  int ks = wg & 1;                     // K half: [0,768) or [768,1536)
  int m0 = (wg / 16) * 384;
  int kb = ks * 768;

  int t = threadIdx.x;
  int lane = t & 63, w = t >> 6;
  int c = lane & 15, g = lane >> 4;
  int wm = w >> 1, wn = w & 1;

  int srow = t >> 3;
  int schunk = ((t & 7) ^ (srow & 7)) * 8;
  const u16* gA = A + (size_t)(m0 + srow) * DIMSZ + schunk;
  const u16* gB = Bt + (size_t)(nt * 192 + srow) * DIMSZ + schunk;

  int off0 = c * 64 + ((g) ^ (c & 7)) * 8;
  int off1 = c * 64 + ((g + 4) ^ (c & 7)) * 8;

  f32x4 acc[6][6];
  f32x4 zero = {0.f, 0.f, 0.f, 0.f};
  #pragma unroll
  for (int am = 0; am < 6; am++)
    #pragma unroll
    for (int an = 0; an < 6; an++) acc[am][an] = zero;
  bf16x8 Ar[6];
  bf16x8 Br[2][6];

  GEMM384_BODY_K(kb, 768)

  #pragma unroll
  for (int an = 0; an < 6; an++) {
    int ncol = nt * 192 + wn * 96 + (an / 3) * 48 + (an % 3) * 16 + c;
    float bvv = (ks == 0) ? bias[ncol] : 0.f;
    #pragma unroll
    for (int am = 0; am < 6; am++) {
      int rowb = m0 + wm * 96 + (am / 3) * 48 + (am % 3) * 16 + 4 * g;
      #pragma unroll
      for (int r = 0; r < 4; r++) {
        int row = rowb + r;
        if (row < LSEQ) atomicAdd(&outF[(size_t)row * DIMSZ + ncol], acc[am][an][r] + bvv);
      }
    }
  }
}

// ---------------- RMSNorm + RoPE, in place ----------------
__launch_bounds__(256)
__global__ void normrope_kernel(u16* __restrict__ Qb, u16* __restrict__ Kb,
                                const float* __restrict__ gq, const float* __restrict__ gk,
                                const float* __restrict__ freqs, const float* __restrict__ freqs_a,
                                const float* __restrict__ freqs_s) {
  int l = blockIdx.x;
  int sel = blockIdx.y;
  u16* P = sel ? Kb : Qb;
  const float* gvec = sel ? gk : gq;
  int t = threadIdx.x;
  u16* row = P + (size_t)l * DIMSZ;
  float xv[6];
  #pragma unroll
  for (int i = 0; i < 3; i++) {
    int p = i * 256 + t;
    ushort2 u = *(const ushort2*)(row + 2 * p);
    xv[2 * i] = b2f(u.x);
    xv[2 * i + 1] = b2f(u.y);
  }
  float ss = 0.f;
  #pragma unroll
  for (int i = 0; i < 6; i++) ss += xv[i] * xv[i];
  #pragma unroll
  for (int d = 32; d; d >>= 1) ss += __shfl_down(ss, d);
  __shared__ float red[4];
  __shared__ float rshare;
  if ((t & 63) == 0) red[t >> 6] = ss;
  __syncthreads();
  if (t == 0) rshare = rsqrtf((red[0] + red[1] + red[2] + red[3]) * (1.0f / DIMSZ) + 1e-6f);
  __syncthreads();
  float rms = rshare;

  const float* f = (l < 3584) ? (freqs + (size_t)l * HEADD)
                : (l < 3680) ? (freqs_a + (size_t)(l - 3584) * HEADD)
                             : (freqs_s + (size_t)(l - 3680) * HEADD);
  #pragma unroll
  for (int i = 0; i < 3; i++) {
    int p = i * 256 + t;
    int j = p & 63;
    float2 csn = *(const float2*)(f + 2 * j);
    float2 gv = *(const float2*)(gvec + 2 * p);
    float xr = xv[2 * i] * rms * gv.x;
    float xi = xv[2 * i + 1] * rms * gv.y;
    ushort2 o;
    o.x = f2b(xr * csn.x - xi * csn.y);
    o.y = f2b(xr * csn.y + xi * csn.x);
    *(ushort2*)(row + 2 * p) = o;
  }
}

// ---------------- fused attention: tail blocks (bx<84) + dense blocks ----------------
#define PSLOT_U16 16640   // 128*128 bf16 O + 128 f32 l
#define NTAIL 84
__launch_bounds__(256, 2)
__global__ void attn_fused_kernel(const u16* __restrict__ Q, const u16* __restrict__ K,
                                  const u16* __restrict__ Vt, u16* __restrict__ O,
                                  u16* __restrict__ DP, float* __restrict__ Part) {
  __shared__ __align__(16) u16 Ks[2][32 * 136];
  __shared__ __align__(16) u16 Vs[2][128 * 40];
  __shared__ __align__(16) u16 Pl[4][32 * 40];

  int t = threadIdx.x, lane = t & 63, w = t >> 6, g = lane >> 4, c = lane & 15;
  const float c1 = SM_SCALE * 1.44269504088896340f;
  const float c2 = 12.0f * 1.44269504088896340f;

  f32x4 zero = {0.f, 0.f, 0.f, 0.f};
  bf16x8 onesv;
  {
    u16 ob = 0x3F80;
    #pragma unroll
    for (int i = 0; i < 8; i++) onesv[i] = ((const __bf16*)&ob)[0];
  }

  if (blockIdx.x < NTAIL) {
    // ================= tail path (action+state rows), reg-pipeline =================
    char* smem = (char*)&Ks[0][0];          // 20608 B used, fits in 48128
    float* Lsum = (float*)(smem + 20608);   // 128 B

    int j = blockIdx.x;
    int bxx = j % 7;
    int h = j / 7;
    int qt, part;
    if (bxx < 3) { qt = 112 + bxx; part = 0; }
    else if (bxx < 6) { qt = 112 + (bxx - 3); part = 1; }
    else { qt = 115; part = 0; }
    int qbase = qt * 32;
    bool heavy = (qt <= 114);

    int S0, E0, S1, E1, S2, E2, S3, E3, niv;
    if (qbase < 3680) {
      int b = (qbase - 3584) >> 5;
      int ibe = 512 + (b + 1) * 1024;
      int kv = imax(512, ibe - 2048);
      S0 = 0; E0 = 512; S1 = kv; E1 = ibe;
      S2 = 3584 + 32 * b; E2 = S2 + 32; S3 = 3680 + b; E3 = S3 + 1; niv = 4;
    } else {
      S0 = 3680; E0 = 3683; S1 = S2 = S3 = 0; E1 = E2 = E3 = 0; niv = 1;
    }
    bool diag = (qbase >= 3680);

    int B0 = S0 & ~31, B1 = S1 & ~31, B2 = S2 & ~31, B3 = S3 & ~31;
    int T1 = (E0 - B0 + 31) >> 5;
    int T2 = T1 + ((niv > 1) ? ((E1 - B1 + 31) >> 5) : 0);
    int T3 = T2 + ((niv > 2) ? ((E2 - B2 + 31) >> 5) : 0);
    int T4 = T3 + ((niv > 3) ? ((E3 - B3 + 31) >> 5) : 0);
    int ntile = T4;

    int rlo = 0, rhi = ntile;
    if (heavy) { int half = (ntile + 1) >> 1; if (part == 0) rhi = half; else rlo = half; }

    auto tile_of = [&](int f, int& k0, int& lo, int& hi) {
      k0 = B0 + (f << 5); lo = S0; hi = E0;
      if (niv > 1 && f >= T1) { k0 = B1 + ((f - T1) << 5); lo = S1; hi = E1; }
      if (niv > 2 && f >= T2) { k0 = B2 + ((f - T2) << 5); lo = S2; hi = E2; }
      if (niv > 3 && f >= T3) { k0 = B3 + ((f - T3) << 5); lo = S3; hi = E3; }
    };

    bf16x8 qf[2][4];
    #pragma unroll
    for (int a = 0; a < 2; a++) {
      const u16* qp = Q + (size_t)(qbase + a * 16 + c) * DIMSZ + h * HEADD + 8 * g;
      #pragma unroll
      for (int s = 0; s < 4; s++) qf[a][s] = *(const bf16x8*)(qp + 32 * s);
    }

    f32x4 acc[2][8];
    f32x4 lacc[2];
    #pragma unroll
    for (int a = 0; a < 2; a++) {
      lacc[a] = zero;
      #pragma unroll
      for (int cc = 0; cc < 8; cc++) acc[a][cc] = zero;
    }

    u16* PwA = (u16*)smem + w * 2560;
    u16* PwB = PwA + 1280;

    bf16x8 kc[2][4], vbuf[8], pa0, pa1;

    auto loadK = [&](int k0) {
      #pragma unroll
      for (int k2 = 0; k2 < 2; k2++) {
        const u16* kp = K + (size_t)(k0 + 16 * k2 + c) * DIMSZ + h * HEADD + 8 * g;
        #pragma unroll
        for (int s = 0; s < 4; s++) kc[k2][s] = *(const bf16x8*)(kp + 32 * s);
      }
    };
    auto loadV = [&](int k0) {
      #pragma unroll
      for (int cc = 0; cc < 8; cc++)
        vbuf[cc] = *(const bf16x8*)(Vt + (size_t)(h * HEADD + cc * 16 + c) * LPAD + k0 + 8 * g);
    };
    auto QKf = [&](f32x4 (&sc)[2][2]) {
      sc[0][0] = zero; sc[0][1] = zero; sc[1][0] = zero; sc[1][1] = zero;
      #pragma unroll
      for (int k2 = 0; k2 < 2; k2++)
        #pragma unroll
        for (int s = 0; s < 4; s++) {
          sc[0][k2] = __builtin_amdgcn_mfma_f32_16x16x32_bf16(qf[0][s], kc[k2][s], sc[0][k2], 0, 0, 0);
          sc[1][k2] = __builtin_amdgcn_mfma_f32_16x16x32_bf16(qf[1][s], kc[k2][s], sc[1][k2], 0, 0, 0);
        }
    };
    auto smstore = [&](f32x4 (&sc)[2][2], int k0, int lo, int hi, u16* Pw) {
      #pragma unroll
      for (int a = 0; a < 2; a++)
        #pragma unroll
        for (int k2 = 0; k2 < 2; k2++) {
          int k = k0 + k2 * 16 + c;
          bool valid = (k >= lo) && (k < hi);
          #pragma unroll
          for (int r = 0; r < 4; r++) {
            float p = __builtin_amdgcn_exp2f(sc[a][k2][r] * c1 - c2);
            bool v = valid;
            if (diag) { int qr = qbase + a * 16 + 4 * g + r; v = v && (k == qr); }
            Pw[(a * 16 + 4 * g + r) * 40 + k2 * 16 + c] = v ? f2b(p) : (u16)0;
          }
        }
    };
    auto readP = [&](u16* Pw) {
      pa0 = *(const bf16x8*)&Pw[c * 40 + 8 * g];
      pa1 = *(const bf16x8*)&Pw[(16 + c) * 40 + 8 * g];
    };
    auto PV = [&]() {
      #pragma unroll
      for (int cc = 0; cc < 8; cc++) {
        acc[0][cc] = __builtin_amdgcn_mfma_f32_16x16x32_bf16(pa0, vbuf[cc], acc[0][cc], 0, 0, 0);
        acc[1][cc] = __builtin_amdgcn_mfma_f32_16x16x32_bf16(pa1, vbuf[cc], acc[1][cc], 0, 0, 0);
      }
      lacc[0] = __builtin_amdgcn_mfma_f32_16x16x32_bf16(pa0, onesv, lacc[0], 0, 0, 0);
      lacc[1] = __builtin_amdgcn_mfma_f32_16x16x32_bf16(pa1, onesv, lacc[1], 0, 0, 0);
    };

    int i = rlo + w;
    if (i < rhi) {
      int ik0, ilo, ihi; tile_of(i, ik0, ilo, ihi);
      loadK(ik0);
      loadV(ik0);
      {
        f32x4 sc[2][2]; QKf(sc);
        smstore(sc, ik0, ilo, ihi, PwA);
      }
      asm volatile("s_waitcnt lgkmcnt(0)" ::: "memory");
      __builtin_amdgcn_sched_barrier(0);
      readP(PwA);
      int nx = i + 4;
      int nk0 = 0, nlo = 0, nhi = 0;
      bool useB = true;
      if (nx < rhi) { tile_of(nx, nk0, nlo, nhi); loadK(nk0); }
      while (nx < rhi) {
        int ck0 = nk0, clo = nlo, chi = nhi;
        f32x4 sc[2][2]; QKf(sc);
        int nn = nx + 4;
        if (nn < rhi) { tile_of(nn, nk0, nlo, nhi); loadK(nk0); }
        u16* Pw = useB ? PwB : PwA;
        smstore(sc, ck0, clo, chi, Pw);
        PV();
        loadV(ck0);
        asm volatile("s_waitcnt lgkmcnt(0)" ::: "memory");
        __builtin_amdgcn_sched_barrier(0);
        readP(Pw);
        useB = !useB;
        i = nx; nx = nn;
      }
      PV();
    }

    __syncthreads();
    float* Oacc = (float*)smem;
    if (w == 0) {
      #pragma unroll
      for (int a = 0; a < 2; a++) {
        #pragma unroll
        for (int cc = 0; cc < 8; cc++)
          #pragma unroll
          for (int r = 0; r < 4; r++)
            Oacc[(a * 16 + 4 * g + r) * 132 + cc * 16 + c] = acc[a][cc][r];
        if (c == 0)
          #pragma unroll
          for (int r = 0; r < 4; r++) Lsum[a * 16 + 4 * g + r] = lacc[a][r];
      }
    }
    __syncthreads();
    #pragma unroll
    for (int ww = 1; ww < 4; ww++) {
      if (w == ww) {
        #pragma unroll
        for (int a = 0; a < 2; a++) {
          #pragma unroll
          for (int cc = 0; cc < 8; cc++)
            #pragma unroll
            for (int r = 0; r < 4; r++)
              Oacc[(a * 16 + 4 * g + r) * 132 + cc * 16 + c] += acc[a][cc][r];
          if (c == 0)
            #pragma unroll
            for (int r = 0; r < 4; r++) Lsum[a * 16 + 4 * g + r] += lacc[a][r];
        }
      }
      __syncthreads();
    }

    int row = t >> 3, c0 = (t & 7) * 16;
    if (heavy) {
      size_t slot = ((size_t)((qt - 112) * 12 + h)) * 2 + part;
      float* P = Part + slot * 4160;
      #pragma unroll
      for (int jj = 0; jj < 16; jj += 4)
        *(float4*)&P[row * 128 + c0 + jj] = *(float4*)&Oacc[row * 132 + c0 + jj];
      if ((t & 7) == 0) P[4096 + row] = Lsum[row];
    } else {
      int orow = qbase + row;
      if (orow < LSEQ) {
        float lsv = Lsum[row];
        float inv = (lsv > 0.f) ? 1.0f / lsv : 0.f;
        u16 tmp[16];
        #pragma unroll
        for (int jj = 0; jj < 16; jj++) tmp[jj] = f2b(Oacc[row * 132 + c0 + jj] * inv);
        u16* op = O + (size_t)orow * DIMSZ + h * HEADD + c0;
        *(uint4*)(op) = *(uint4*)&tmp[0];
        *(uint4*)(op + 8) = *(uint4*)&tmp[8];
      }
    }
    return;
  }

  // ================= dense path (staged shared-KV flash, R11-proven) =================
  int bx = blockIdx.x - NTAIL;
  int qbase, h, part, nparts, fb;
  if (bx < 48) { qbase = (bx / 12) * 128; h = bx % 12; part = 0; nparts = 1; fb = -1; }
  else if (bx < 336) { int i = bx - 48; int qb = i / 36; h = (i / 3) % 12; part = i % 3; nparts = 3; fb = 0; qbase = 512 + qb * 128; }
  else if (bx < 720) { int i = bx - 336; int qb = i / 48; h = (i / 4) % 12; part = i % 4; nparts = 4; fb = 1; qbase = 1536 + qb * 128; }
  else { int i = bx - 720; int qb = i / 48; h = (i / 4) % 12; part = i % 4; nparts = 4; fb = 2; qbase = 2560 + qb * 128; }

  int S0, E0, S1, E1, S2, E2, S3, E3, niv;
  if (fb < 0) { S0 = 0; E0 = 512; S1 = E1 = S2 = E2 = S3 = E3 = 0; niv = 1; }
  else {
    int be = 512 + (fb + 1) * 1024;
    int kv = imax(512, be - 2048);
    S0 = 0; E0 = 512; S1 = kv; E1 = be;
    S2 = 3584 + 32 * fb; E2 = S2 + 32; S3 = 3680 + fb; E3 = S3 + 1; niv = 4;
  }
  int B0 = S0 & ~31, B1 = S1 & ~31, B2 = S2 & ~31, B3 = S3 & ~31;
  int T1 = (E0 - B0 + 31) >> 5;
  int T2 = T1 + ((niv > 1) ? ((E1 - B1 + 31) >> 5) : 0);
  int T3 = T2 + ((niv > 2) ? ((E2 - B2 + 31) >> 5) : 0);
  int T4 = T3 + ((niv > 3) ? ((E3 - B3 + 31) >> 5) : 0);
  int ntile = T4;
  int rlo = (ntile * part) / nparts, rhi = (ntile * (part + 1)) / nparts;

  auto tile_of = [&](int f, int& k0, int& lo, int& hi) {
    k0 = B0 + (f << 5); lo = S0; hi = E0;
    if (niv > 1 && f >= T1) { k0 = B1 + ((f - T1) << 5); lo = S1; hi = E1; }
    if (niv > 2 && f >= T2) { k0 = B2 + ((f - T2) << 5); lo = S2; hi = E2; }
    if (niv > 3 && f >= T3) { k0 = B3 + ((f - T3) << 5); lo = S3; hi = E3; }
  };

  const u16* kgp = K + (size_t)(t >> 3) * DIMSZ + h * HEADD + 8 * (t & 7);
  int kds = (t >> 3) * 136 + 8 * (t & 7);
  const u16* vgp = Vt + ((size_t)h * HEADD + (t >> 1)) * LPAD + 16 * (t & 1);
  int vds = (t >> 1) * 40 + 16 * (t & 1);

  uint4 sk0, sk1, sv0, sv1;
  auto stage_load = [&](int k0) {
    const u16* kp = kgp + (size_t)k0 * DIMSZ;
    sk0 = *(const uint4*)(kp);
    sk1 = *(const uint4*)(kp + 64);
    sv0 = *(const uint4*)(vgp + k0);
    sv1 = *(const uint4*)(vgp + k0 + 8);
  };
  auto stage_write = [&](int buf) {
    *(uint4*)&Ks[buf][kds] = sk0;
    *(uint4*)&Ks[buf][kds + 64] = sk1;
    *(uint4*)&Vs[buf][vds] = sv0;
    *(uint4*)&Vs[buf][vds + 8] = sv1;
  };

  int qrow0 = qbase + 32 * w;
  bf16x8 qf[2][4];
  #pragma unroll
  for (int a = 0; a < 2; a++) {
    const u16* qp = Q + (size_t)(qrow0 + a * 16 + c) * DIMSZ + h * HEADD + 8 * g;
    #pragma unroll
    for (int s = 0; s < 4; s++) qf[a][s] = *(const bf16x8*)(qp + 32 * s);
  }

  f32x4 acc[2][8];
  f32x4 lacc[2];
  #pragma unroll
  for (int a = 0; a < 2; a++) {
    lacc[a] = zero;
    #pragma unroll
    for (int cc = 0; cc < 8; cc++) acc[a][cc] = zero;
  }

  u16* Pw = &Pl[w][0];
  __bf16* Pwh = (__bf16*)Pw;

  {
    int k0, lo, hi; tile_of(rlo, k0, lo, hi);
    stage_load(k0);
    stage_write(0);
  }
  __syncthreads();
  int cur = 0;

  for (int tt = rlo; tt < rhi; ++tt) {
    int ck0, clo, chi; tile_of(tt, ck0, clo, chi);
    bool pre = (tt + 1 < rhi);
    if (pre) { int nk0, nl, nh; tile_of(tt + 1, nk0, nl, nh); stage_load(nk0); }

    f32x4 sc[2][2];
    sc[0][0] = zero; sc[0][1] = zero; sc[1][0] = zero; sc[1][1] = zero;
    #pragma unroll
    for (int k2 = 0; k2 < 2; k2++)
      #pragma unroll
      for (int s = 0; s < 4; s++) {
        bf16x8 kf = *(const bf16x8*)&Ks[cur][(16 * k2 + c) * 136 + 32 * s + 8 * g];
        sc[0][k2] = __builtin_amdgcn_mfma_f32_16x16x32_bf16(qf[0][s], kf, sc[0][k2], 0, 0, 0);
        sc[1][k2] = __builtin_amdgcn_mfma_f32_16x16x32_bf16(qf[1][s], kf, sc[1][k2], 0, 0, 0);
      }

    if (ck0 >= clo && ck0 + 32 <= chi) {
      // interior tile: no masking, native bf16 cvt
      #pragma unroll
      for (int a = 0; a < 2; a++)
        #pragma unroll
        for (int k2 = 0; k2 < 2; k2++)
          #pragma unroll
          for (int r = 0; r < 4; r++) {
            float p = __builtin_amdgcn_exp2f(sc[a][k2][r] * c1 - c2);
            Pwh[(a * 16 + 4 * g + r) * 40 + k2 * 16 + c] = (__bf16)p;
          }
    } else {
      #pragma unroll
      for (int a = 0; a < 2; a++)
        #pragma unroll
        for (int k2 = 0; k2 < 2; k2++) {
          int k = ck0 + k2 * 16 + c;
          bool valid = (k >= clo) && (k < chi);
          #pragma unroll
          for (int r = 0; r < 4; r++) {
            float p = __builtin_amdgcn_exp2f(sc[a][k2][r] * c1 - c2);
            Pwh[(a * 16 + 4 * g + r) * 40 + k2 * 16 + c] = valid ? (__bf16)p : (__bf16)0.0f;
          }
        }
    }
    asm volatile("s_waitcnt lgkmcnt(0)" ::: "memory");
    __builtin_amdgcn_sched_barrier(0);

    bf16x8 pa0 = *(const bf16x8*)&Pw[c * 40 + 8 * g];
    bf16x8 pa1 = *(const bf16x8*)&Pw[(16 + c) * 40 + 8 * g];

    #pragma unroll
    for (int cc = 0; cc < 8; cc++) {
      bf16x8 vf = *(const bf16x8*)&Vs[cur][(cc * 16 + c) * 40 + 8 * g];
      acc[0][cc] = __builtin_amdgcn_mfma_f32_16x16x32_bf16(pa0, vf, acc[0][cc], 0, 0, 0);
      acc[1][cc] = __builtin_amdgcn_mfma_f32_16x16x32_bf16(pa1, vf, acc[1][cc], 0, 0, 0);
    }
    lacc[0] = __builtin_amdgcn_mfma_f32_16x16x32_bf16(pa0, onesv, lacc[0], 0, 0, 0);
    lacc[1] = __builtin_amdgcn_mfma_f32_16x16x32_bf16(pa1, onesv, lacc[1], 0, 0, 0);

    if (pre) stage_write(cur ^ 1);
    __syncthreads();
    cur ^= 1;
  }

  if (nparts == 1) {
    float inv[2][4];
    #pragma unroll
    for (int a = 0; a < 2; a++)
      #pragma unroll
      for (int r = 0; r < 4; r++) inv[a][r] = (lacc[a][r] > 0.f) ? 1.0f / lacc[a][r] : 0.f;
    #pragma unroll
    for (int a = 0; a < 2; a++)
      #pragma unroll
      for (int cc = 0; cc < 8; cc++)
        #pragma unroll
        for (int r = 0; r < 4; r++) {
          int row = qrow0 + a * 16 + 4 * g + r;
          O[(size_t)row * DIMSZ + h * HEADD + cc * 16 + c] = f2b(acc[a][cc][r] * inv[a][r]);
        }
  } else {
    int qb = (qbase - 512 - fb * 1024) >> 7;
    int sbase = (fb == 0) ? 0 : (fb == 1 ? 288 : 672);
    int slot = sbase + (qb * 12 + h) * nparts + part;
    u16* DPs = DP + (size_t)slot * PSLOT_U16;
    float* lout = (float*)(DPs + 16384);
    #pragma unroll
    for (int a = 0; a < 2; a++) {
      #pragma unroll
      for (int cc = 0; cc < 8; cc++)
        #pragma unroll
        for (int r = 0; r < 4; r++)
          DPs[(32 * w + a * 16 + 4 * g + r) * 128 + cc * 16 + c] = f2b(acc[a][cc][r]);
      if (c == 0)
        #pragma unroll
        for (int r = 0; r < 4; r++) lout[32 * w + a * 16 + 4 * g + r] = lacc[a][r];
    }
  }
}

// ---------------- fused merge: dense partials (bx<24) + tail partials ----------------
__launch_bounds__(256)
__global__ void attn_merge_kernel(const u16* __restrict__ DP, const float* __restrict__ Part,
                                  u16* __restrict__ O) {
  int bx = blockIdx.x, h = blockIdx.y;
  int T = threadIdx.x;
  if (bx < 24) {
    int qi = bx;
    int fb = qi >> 3, qb = qi & 7;
    int nparts = (fb == 0) ? 3 : 4;
    int sbase = (fb == 0) ? 0 : (fb == 1 ? 288 : 672);
    int slot0 = sbase + (qb * 12 + h) * nparts;
    int qbase = 512 + fb * 1024 + qb * 128;
    int row = T >> 1, c0 = 64 * (T & 1);

    float sum[64];
    #pragma unroll
    for (int j = 0; j < 64; j++) sum[j] = 0.f;
    float l = 0.f;
    for (int p = 0; p < nparts; p++) {
      const u16* S = DP + (size_t)(slot0 + p) * PSLOT_U16;
      l += ((const float*)(S + 16384))[row];
      #pragma unroll
      for (int j = 0; j < 64; j += 8) {
        uint4 v = *(const uint4*)&S[row * 128 + c0 + j];
        const u16* pv = (const u16*)&v;
        #pragma unroll
        for (int q = 0; q < 8; q++) sum[j + q] += b2f(pv[q]);
      }
    }
    float inv = (l > 0.f) ? 1.0f / l : 0.f;
    u16 tmp[64];
    #pragma unroll
    for (int j = 0; j < 64; j++) tmp[j] = f2b(sum[j] * inv);
    u16* op = O + (size_t)(qbase + row) * DIMSZ + h * HEADD + c0;
    #pragma unroll
    for (int j = 0; j < 64; j += 8) *(uint4*)(op + j) = *(uint4*)&tmp[j];
  } else {
    int b = bx - 24;
    const float* A = Part + ((size_t)(b * 12 + h)) * 2 * 4160;
    const float* B = A + 4160;
    int row = T >> 3, c0 = (T & 7) * 16;
    float l = A[4096 + row] + B[4096 + row];
    float inv = (l > 0.f) ? 1.0f / l : 0.f;
    int orow = 3584 + b * 32 + row;
    u16 tmp[16];
    #pragma unroll
    for (int jj = 0; jj < 16; jj += 4) {
      float4 va = *(const float4*)&A[row * 128 + c0 + jj];
      float4 vb = *(const float4*)&B[row * 128 + c0 + jj];
      tmp[jj + 0] = f2b((va.x + vb.x) * inv);
      tmp[jj + 1] = f2b((va.y + vb.y) * inv);
      tmp[jj + 2] = f2b((va.z + vb.z) * inv);
      tmp[jj + 3] = f2b((va.w + vb.w) * inv);
    }
    u16* op = O + (size_t)orow * DIMSZ + h * HEADD + c0;
    *(uint4*)(op) = *(uint4*)&tmp[0];
    *(uint4*)(op + 8) = *(uint4*)&tmp[8];
  }
}

// ---------------- launch ----------------
extern "C" void kernel_launch(void* const* d_in, const int* in_sizes, int n_in,
                              void* d_out, int out_size, void* d_ws, size_t ws_size,
                              hipStream_t stream) {
  (void)in_sizes; (void)n_in; (void)out_size; (void)ws_size;
  const float* x       = (const float*)d_in[0];
  const float* freqs   = (const float*)d_in[1];
  const float* freqs_a = (const float*)d_in[2];
  const float* freqs_s = (const float*)d_in[3];
  const float* Wq = (const float*)d_in[4];
  const float* bq = (const float*)d_in[5];
  const float* Wk = (const float*)d_in[6];
  const float* bk = (const float*)d_in[7];
  const float* Wv = (const float*)d_in[8];
  const float* bv = (const float*)d_in[9];
  const float* Wo = (const float*)d_in[10];
  const float* bo = (const float*)d_in[11];
  const float* gq = (const float*)d_in[12];
  const float* gk = (const float*)d_in[13];
  float* out = (float*)d_out;

  char* ws = (char*)d_ws;
  size_t off = 0;
  auto alloc = [&](size_t bytes) -> void* {
    void* p = ws + off;
    off += (bytes + 255) & ~(size_t)255;
    return p;
  };
  u16* xb   = (u16*)alloc((size_t)LPAD * DIMSZ * 2);
  u16* Wt   = (u16*)alloc((size_t)4 * DIMSZ * DIMSZ * 2);
  u16* Qb   = (u16*)alloc((size_t)LPAD * DIMSZ * 2);
  u16* Kb   = (u16*)alloc((size_t)LPAD * DIMSZ * 2);
  u16* Vt   = (u16*)alloc((size_t)DIMSZ * LPAD * 2);
  u16* Ob   = (u16*)alloc((size_t)LPAD * DIMSZ * 2);
  u16* DP   = (u16*)alloc((size_t)1056 * PSLOT_U16 * 2);
  float* PartT = (float*)alloc((size_t)3 * 12 * 2 * 4160 * 4);

  // zero out for K-split atomic accumulation (capture-legal, idempotent)
  hipMemsetAsync(out, 0, (size_t)LSEQ * DIMSZ * sizeof(float), stream);

  prep_kernel<<<dim3(CONV_BLOCKS + 9216), 256, 0, stream>>>(x, xb, Wq, Wk, Wv, Wo, Wt);

  gemm_qkv384_kernel<<<dim3(240), 512, 0, stream>>>(xb, Wt, bq, bk, bv, Qb, Kb, Vt);

  normrope_kernel<<<dim3(LSEQ, 2), 256, 0, stream>>>(Qb, Kb, gq, gk, freqs, freqs_a, freqs_s);

  attn_fused_kernel<<<dim3(NTAIL + 1104), 256, 0, stream>>>(Qb, Kb, Vt, Ob, DP, PartT);
  attn_merge_kernel<<<dim3(27, 12), 256, 0, stream>>>(DP, PartT, Ob);

  gemm_out384_kernel<<<dim3(160), 512, 0, stream>>>(Ob, Wt + 3 * (size_t)DIMSZ * DIMSZ, bo, out);
}

// Round 11
// 217.593 us; speedup vs baseline: 1.1796x; 1.1796x over previous
//
// R16: revert R15's atomic gemm_out (refuted: +18us). gemm_out retiled
// 384x192 -> 192x192: 20x8 = 160 blocks (was 80 = 31% CU util). 4-phase
// variant of the proven template: 8 waves 2x4, wave tile 96x48, LDS 96KB,
// stage order A(2i+1)@P1, B(2i+2)@P2, A(2i+2)@P3, B(2i+3)@P4, vmcnt(3)
// at P2/P4 (FIFO-traced from prologue), peel vmcnt(0)@P2. A-side macros
// reused; B single 48-col group. Everything else identical to R13 (238.7us).
#include <hip/hip_runtime.h>

#define LSEQ 3683
#define LPAD 3840
#define DIMSZ 1536
#define NHEAD 12
#define HEADD 128
#define SM_SCALE 0.088388347648318447f   // 1/sqrt(128)

typedef unsigned short u16;
typedef unsigned int u32;
typedef __bf16 bf16x8 __attribute__((ext_vector_type(8)));
typedef float f32x4 __attribute__((ext_vector_type(4)));

__device__ __forceinline__ u16 f2b(float f) {
  u32 u = __float_as_uint(f);
  u += 0x7FFFu + ((u >> 16) & 1u);   // RNE
  return (u16)(u >> 16);
}
__device__ __forceinline__ float b2f(u16 s) {
  return __uint_as_float(((u32)s) << 16);
}
__device__ __forceinline__ int imax(int a, int b) { return a > b ? a : b; }

// async global->LDS, 16B per lane; lds base must be wave-uniform.
__device__ __forceinline__ void gl_lds16(const u16* g, u16* l) {
  __builtin_amdgcn_global_load_lds((const __attribute__((address_space(1))) u32*)g,
                                   (__attribute__((address_space(3))) u32*)l,
                                   16, 0, 0);
}

// bijective XCD-chunk swizzle (m204): round-robin orig -> contiguous chunks.
__device__ __forceinline__ int xcd_swz(int orig, int nwg) {
  int q = nwg >> 3, r = nwg & 7;
  int x = orig & 7, l = orig >> 3;
  return (x < r ? x * (q + 1) : r * (q + 1) + (x - r) * q) + l;
}

// ---------------- fused prep: x f32->bf16 pad + W transposes ----------------
#define CONV_BLOCKS 5760   // (LPAD*DIMSZ/4)/256
__global__ void prep_kernel(const float* __restrict__ x, u16* __restrict__ xb,
                            const float* __restrict__ W0, const float* __restrict__ W1,
                            const float* __restrict__ W2, const float* __restrict__ W3,
                            u16* __restrict__ Wt) {
  __shared__ float tile[32][33];
  int bx = blockIdx.x;
  if (bx < CONV_BLOCKS) {
    long idx = (long)bx * blockDim.x + threadIdx.x;
    long base = idx * 4;
    if (base >= (long)LPAD * DIMSZ) return;
    float4 v;
    if (base < (long)LSEQ * DIMSZ) v = *(const float4*)(x + base);
    else v = make_float4(0.f, 0.f, 0.f, 0.f);
    ushort4 o;
    o.x = f2b(v.x); o.y = f2b(v.y); o.z = f2b(v.z); o.w = f2b(v.w);
    *(ushort4*)(xb + base) = o;
  } else {
    int i = bx - CONV_BLOCKS;
    int z = i / 2304;               // 48*48 per matrix
    int r = i % 2304;
    int bxx = r % 48, byy = r / 48;
    const float* W = (z == 0) ? W0 : (z == 1) ? W1 : (z == 2) ? W2 : W3;
    u16* dst = Wt + (size_t)z * DIMSZ * DIMSZ;
    int k0 = bxx * 32, n0 = byy * 32;
    int tx = threadIdx.x & 31, ty = threadIdx.x >> 5;
    #pragma unroll
    for (int q = 0; q < 4; q++) {
      int k = k0 + ty + q * 8;
      tile[ty + q * 8][tx] = W[(size_t)k * DIMSZ + n0 + tx];
    }
    __syncthreads();
    #pragma unroll
    for (int q = 0; q < 4; q++) {
      int n = n0 + ty + q * 8;
      dst[(size_t)n * DIMSZ + k0 + tx] = f2b(tile[tx][ty + q * 8]);
    }
  }
}

// ================== shared GEMM building blocks ==================
#define BAR() __builtin_amdgcn_s_barrier()
#define LGK0() asm volatile("s_waitcnt lgkmcnt(0)" ::: "memory")
#define LGK8() asm volatile("s_waitcnt lgkmcnt(8)" ::: "memory")
#define VMC9() asm volatile("s_waitcnt vmcnt(9)" ::: "memory")
#define VMC6() asm volatile("s_waitcnt vmcnt(6)" ::: "memory")
#define VMC3() asm volatile("s_waitcnt vmcnt(3)" ::: "memory")
#define VMC0() asm volatile("s_waitcnt vmcnt(0)" ::: "memory")
#define PRIO1() __builtin_amdgcn_s_setprio(1)
#define PRIO0() __builtin_amdgcn_s_setprio(0)

// one 64-row staging issue (512 threads x 16B = 64 rows of 128B)
#define STG_A(buf, q, kt) \
  gl_lds16(gA + (size_t)((q) * 64) * DIMSZ + (kt), &Asg[buf][((q) * 64 + w * 8) * 64]);
#define STG_B(buf, q, kt) \
  gl_lds16(gB + (size_t)((q) * 64) * DIMSZ + (kt), &Bsg[buf][((q) * 64 + w * 8) * 64]);

// ds-read register subtiles (swizzled offsets off0/off1); 6 ds_read_b128 each
#define LDA3(buf, mh) { \
  _Pragma("unroll") for (int mf = 0; mf < 3; mf++) { \
    int rb = (wm * 96 + (mh) * 48 + mf * 16) * 64; \
    Ar[mf * 2 + 0] = *(const bf16x8*)&Asg[buf][rb + off0]; \
    Ar[mf * 2 + 1] = *(const bf16x8*)&Asg[buf][rb + off1]; } }
#define LDB3(buf, nh) { \
  _Pragma("unroll") for (int nf = 0; nf < 3; nf++) { \
    int rb = (wn * 96 + (nh) * 48 + nf * 16) * 64; \
    Br[nh][nf * 2 + 0] = *(const bf16x8*)&Bsg[buf][rb + off0]; \
    Br[nh][nf * 2 + 1] = *(const bf16x8*)&Bsg[buf][rb + off1]; } }

// one C-quadrant (3x3 frags) x K=64: 18 MFMA (384-template)
#define MFMAQ3(mh, nh) { \
  _Pragma("unroll") for (int mf = 0; mf < 3; mf++) \
    _Pragma("unroll") for (int nf = 0; nf < 3; nf++) { \
      acc[(mh)*3+mf][(nh)*3+nf] = __builtin_amdgcn_mfma_f32_16x16x32_bf16(Ar[mf*2+0], Br[nh][nf*2+0], acc[(mh)*3+mf][(nh)*3+nf], 0, 0, 0); \
      acc[(mh)*3+mf][(nh)*3+nf] = __builtin_amdgcn_mfma_f32_16x16x32_bf16(Ar[mf*2+1], Br[nh][nf*2+1], acc[(mh)*3+mf][(nh)*3+nf], 0, 0, 0); } }

// ======== 384x192 8-phase body (used by gemm_qkv) ========
#define GEMM384_BODY() \
  STG_B(0, 0, 0) STG_B(0, 1, 0) STG_B(0, 2, 0) \
  STG_A(0, 0, 0) STG_A(0, 1, 0) STG_A(0, 2, 0) \
  STG_A(0, 3, 0) STG_A(0, 4, 0) STG_A(0, 5, 0) \
  STG_B(1, 0, 64) STG_B(1, 1, 64) STG_B(1, 2, 64) \
  STG_A(1, 0, 64) STG_A(1, 1, 64) STG_A(1, 2, 64) \
  STG_A(1, 3, 64) STG_A(1, 4, 64) STG_A(1, 5, 64) \
  VMC9(); \
  BAR(); \
  for (int i = 0; i < DIMSZ / 64 / 2 - 1; ++i) { \
    int kt2 = (2 * i + 2) * 64; \
    int kt3 = (2 * i + 3) * 64; \
    LDA3(0, 0) LDB3(0, 0) \
    LGK8(); BAR(); LGK0(); \
    PRIO1(); MFMAQ3(0, 0) PRIO0(); \
    BAR(); \
    LDB3(0, 1) \
    BAR(); LGK0(); \
    PRIO1(); MFMAQ3(0, 1) PRIO0(); \
    BAR(); \
    LDA3(0, 1) \
    STG_B(0, 0, kt2) STG_B(0, 1, kt2) STG_B(0, 2, kt2) \
    BAR(); LGK0(); \
    PRIO1(); MFMAQ3(1, 1) PRIO0(); \
    BAR(); \
    STG_A(0, 0, kt2) STG_A(0, 1, kt2) STG_A(0, 2, kt2) \
    VMC6(); BAR(); \
    PRIO1(); MFMAQ3(1, 0) PRIO0(); \
    BAR(); \
    LDA3(1, 0) LDB3(1, 0) \
    STG_A(0, 3, kt2) STG_A(0, 4, kt2) STG_A(0, 5, kt2) \
    LGK8(); BAR(); LGK0(); \
    PRIO1(); MFMAQ3(0, 0) PRIO0(); \
    BAR(); \
    LDB3(1, 1) \
    BAR(); LGK0(); \
    PRIO1(); MFMAQ3(0, 1) PRIO0(); \
    BAR(); \
    LDA3(1, 1) \
    STG_B(1, 0, kt3) STG_B(1, 1, kt3) STG_B(1, 2, kt3) \
    BAR(); LGK0(); \
    PRIO1(); MFMAQ3(1, 1) PRIO0(); \
    BAR(); \
    STG_A(1, 0, kt3) STG_A(1, 1, kt3) STG_A(1, 2, kt3) \
    STG_A(1, 3, kt3) STG_A(1, 4, kt3) STG_A(1, 5, kt3) \
    VMC9(); BAR(); \
    PRIO1(); MFMAQ3(1, 0) PRIO0(); \
    BAR(); \
  } \
  { \
    LDA3(0, 0) LDB3(0, 0) \
    LGK8(); BAR(); LGK0(); \
    PRIO1(); MFMAQ3(0, 0) PRIO0(); \
    BAR(); \
    LDB3(0, 1) \
    BAR(); LGK0(); \
    PRIO1(); MFMAQ3(0, 1) PRIO0(); \
    BAR(); \
    LDA3(0, 1) \
    BAR(); LGK0(); \
    PRIO1(); MFMAQ3(1, 1) PRIO0(); \
    BAR(); \
    VMC0(); BAR(); \
    PRIO1(); MFMAQ3(1, 0) PRIO0(); \
    BAR(); \
    LDA3(1, 0) LDB3(1, 0) \
    LGK8(); BAR(); LGK0(); \
    PRIO1(); MFMAQ3(0, 0) PRIO0(); \
    BAR(); \
    LDB3(1, 1) \
    BAR(); LGK0(); \
    PRIO1(); MFMAQ3(0, 1) PRIO0(); \
    BAR(); \
    LDA3(1, 1) \
    BAR(); LGK0(); \
    PRIO1(); MFMAQ3(1, 1) PRIO0(); \
    MFMAQ3(1, 0) \
  }

__launch_bounds__(512, 2)
__global__ void gemm_qkv384_kernel(const u16* __restrict__ A, const u16* __restrict__ Wt,
                                   const float* __restrict__ bq, const float* __restrict__ bk,
                                   const float* __restrict__ bv,
                                   u16* __restrict__ Qb, u16* __restrict__ Kb,
                                   u16* __restrict__ Vt) {
  __shared__ __align__(16) u16 Asg[2][384 * 64];
  __shared__ __align__(16) u16 Bsg[2][192 * 64];

  int wg = xcd_swz(blockIdx.x, 10 * 24);
  int nt = wg % 24;                    // 24 col tiles of 192 (8 per matrix)
  int m0 = (wg / 24) * 384;
  int which = nt >> 3;
  const float* bias = (which == 0) ? bq : (which == 1) ? bk : bv;

  int t = threadIdx.x;
  int lane = t & 63, w = t >> 6;       // 8 waves
  int c = lane & 15, g = lane >> 4;
  int wm = w >> 1, wn = w & 1;         // 4x2 wave grid; wave tile 96x96

  int srow = t >> 3;
  int schunk = ((t & 7) ^ (srow & 7)) * 8;
  const u16* gA = A + (size_t)(m0 + srow) * DIMSZ + schunk;
  const u16* gB = Wt + (size_t)(nt * 192 + srow) * DIMSZ + schunk;

  int off0 = c * 64 + ((g) ^ (c & 7)) * 8;
  int off1 = c * 64 + ((g + 4) ^ (c & 7)) * 8;

  f32x4 acc[6][6];
  f32x4 zero = {0.f, 0.f, 0.f, 0.f};
  #pragma unroll
  for (int am = 0; am < 6; am++)
    #pragma unroll
    for (int an = 0; an < 6; an++) acc[am][an] = zero;
  bf16x8 Ar[6];
  bf16x8 Br[2][6];

  GEMM384_BODY()

  // epilogue: bias add + write. Q/K row-major, V transposed (pack 4 rows).
  #pragma unroll
  for (int an = 0; an < 6; an++) {
    int ncol = (nt & 7) * 192 + wn * 96 + (an / 3) * 48 + (an % 3) * 16 + c;
    float bvv = bias[ncol];
    #pragma unroll
    for (int am = 0; am < 6; am++) {
      int rowb = m0 + wm * 96 + (am / 3) * 48 + (am % 3) * 16 + 4 * g;
      if (which == 2) {
        ushort4 pv;
        pv.x = f2b(acc[am][an][0] + bvv);
        pv.y = f2b(acc[am][an][1] + bvv);
        pv.z = f2b(acc[am][an][2] + bvv);
        pv.w = f2b(acc[am][an][3] + bvv);
        *(ushort4*)&Vt[(size_t)ncol * LPAD + rowb] = pv;
      } else {
        u16* P = (which == 1) ? Kb : Qb;
        #pragma unroll
        for (int r = 0; r < 4; r++)
          P[(size_t)(rowb + r) * DIMSZ + ncol] = f2b(acc[am][an][r] + bvv);
      }
    }
  }
}

// ======== 192x192 4-phase final GEMM: 160 blocks, single round ========
// B single 48-col group per wave (wn in 0..3); A reuses LDA3 (wm in 0..1).
#define LDB3S(buf) { \
  _Pragma("unroll") for (int nf = 0; nf < 3; nf++) { \
    int rb = (wn * 48 + nf * 16) * 64; \
    Br2[nf * 2 + 0] = *(const bf16x8*)&Bsg[buf][rb + off0]; \
    Br2[nf * 2 + 1] = *(const bf16x8*)&Bsg[buf][rb + off1]; } }

#define MFMAQ2(mh) { \
  _Pragma("unroll") for (int mf = 0; mf < 3; mf++) \
    _Pragma("unroll") for (int nf = 0; nf < 3; nf++) { \
      acc2[(mh)*3+mf][nf] = __builtin_amdgcn_mfma_f32_16x16x32_bf16(Ar[mf*2+0], Br2[nf*2+0], acc2[(mh)*3+mf][nf], 0, 0, 0); \
      acc2[(mh)*3+mf][nf] = __builtin_amdgcn_mfma_f32_16x16x32_bf16(Ar[mf*2+1], Br2[nf*2+1], acc2[(mh)*3+mf][nf], 0, 0, 0); } }

__launch_bounds__(512, 2)
__global__ void gemm_out192_kernel(const u16* __restrict__ A, const u16* __restrict__ Bt,
                                   const float* __restrict__ bias, float* __restrict__ outF) {
  __shared__ __align__(16) u16 Asg[2][192 * 64];
  __shared__ __align__(16) u16 Bsg[2][192 * 64];

  int wg = xcd_swz(blockIdx.x, 160);
  int nt = wg & 7;                     // 8 col tiles of 192
  int m0 = (wg >> 3) * 192;            // 20 row tiles of 192

  int t = threadIdx.x;
  int lane = t & 63, w = t >> 6;
  int c = lane & 15, g = lane >> 4;
  int wm = w >> 2, wn = w & 3;         // 2x4 wave grid; wave tile 96x48

  int srow = t >> 3;
  int schunk = ((t & 7) ^ (srow & 7)) * 8;
  const u16* gA = A + (size_t)(m0 + srow) * DIMSZ + schunk;
  const u16* gB = Bt + (size_t)(nt * 192 + srow) * DIMSZ + schunk;

  int off0 = c * 64 + ((g) ^ (c & 7)) * 8;
  int off1 = c * 64 + ((g + 4) ^ (c & 7)) * 8;

  f32x4 acc2[6][3];
  f32x4 zero = {0.f, 0.f, 0.f, 0.f};
  #pragma unroll
  for (int am = 0; am < 6; am++)
    #pragma unroll
    for (int an = 0; an < 3; an++) acc2[am][an] = zero;
  bf16x8 Ar[6];
  bf16x8 Br2[6];

  // prologue: tile0 full (B,A), tile1 B only; drain tile0 -> vmcnt(3)
  STG_B(0, 0, 0) STG_B(0, 1, 0) STG_B(0, 2, 0)
  STG_A(0, 0, 0) STG_A(0, 1, 0) STG_A(0, 2, 0)
  STG_B(1, 0, 64) STG_B(1, 1, 64) STG_B(1, 2, 64)
  VMC3();
  BAR();

  // iteration i: computes tiles 2i (buf0), 2i+1 (buf1).
  // Stages: A(2i+1)@P1, B(2i+2)@P2 [+vmcnt(3): tile 2i+1 landed],
  //         A(2i+2)@P3, B(2i+3)@P4 [+vmcnt(3): tile 2i+2 landed].
  for (int i = 0; i < DIMSZ / 64 / 2 - 1; ++i) {
    int ktn1 = (2 * i + 1) * 64;
    int kt2  = (2 * i + 2) * 64;
    int kt3  = (2 * i + 3) * 64;
    // P1: read buf0 (A-mh0 + B), stage A(2i+1) -> Asg[1]
    LDA3(0, 0) LDB3S(0)
    STG_A(1, 0, ktn1) STG_A(1, 1, ktn1) STG_A(1, 2, ktn1)
    LGK8(); BAR(); LGK0();
    PRIO1(); MFMAQ2(0) PRIO0();
    BAR();
    // P2: read buf0 A-mh1, stage B(2i+2) -> Bsg[0]; drain tile 2i+1
    LDA3(0, 1)
    STG_B(0, 0, kt2) STG_B(0, 1, kt2) STG_B(0, 2, kt2)
    VMC3(); BAR(); LGK0();
    PRIO1(); MFMAQ2(1) PRIO0();
    BAR();
    // P3: read buf1 (A-mh0 + B), stage A(2i+2) -> Asg[0]
    LDA3(1, 0) LDB3S(1)
    STG_A(0, 0, kt2) STG_A(0, 1, kt2) STG_A(0, 2, kt2)
    LGK8(); BAR(); LGK0();
    PRIO1(); MFMAQ2(0) PRIO0();
    BAR();
    // P4: read buf1 A-mh1, stage B(2i+3) -> Bsg[1]; drain tile 2i+2
    LDA3(1, 1)
    STG_B(1, 0, kt3) STG_B(1, 1, kt3) STG_B(1, 2, kt3)
    VMC3(); BAR(); LGK0();
    PRIO1(); MFMAQ2(1) PRIO0();
    BAR();
  }

  // peel (tiles 22, 23): stage only A(23)@P1; drain all at P2
  {
    LDA3(0, 0) LDB3S(0)
    STG_A(1, 0, DIMSZ - 64) STG_A(1, 1, DIMSZ - 64) STG_A(1, 2, DIMSZ - 64)
    LGK8(); BAR(); LGK0();
    PRIO1(); MFMAQ2(0) PRIO0();
    BAR();
    LDA3(0, 1)
    VMC0(); BAR(); LGK0();
    PRIO1(); MFMAQ2(1) PRIO0();
    BAR();
    LDA3(1, 0) LDB3S(1)
    LGK8(); BAR(); LGK0();
    PRIO1(); MFMAQ2(0) PRIO0();
    BAR();
    LDA3(1, 1)
    LGK0();
    MFMAQ2(1)
  }

  #pragma unroll
  for (int an = 0; an < 3; an++) {
    int ncol = nt * 192 + wn * 48 + an * 16 + c;
    float bvv = bias[ncol];
    #pragma unroll
    for (int am = 0; am < 6; am++) {
      int rowb = m0 + wm * 96 + (am / 3) * 48 + (am % 3) * 16 + 4 * g;
      #pragma unroll
      for (int r = 0; r < 4; r++) {
        int row = rowb + r;
        if (row < LSEQ) outF[(size_t)row * DIMSZ + ncol] = acc2[am][an][r] + bvv;
      }
    }
  }
}

// ---------------- RMSNorm + RoPE, in place ----------------
__launch_bounds__(256)
__global__ void normrope_kernel(u16* __restrict__ Qb, u16* __restrict__ Kb,
                                const float* __restrict__ gq, const float* __restrict__ gk,
                                const float* __restrict__ freqs, const float* __restrict__ freqs_a,
                                const float* __restrict__ freqs_s) {
  int l = blockIdx.x;
  int sel = blockIdx.y;
  u16* P = sel ? Kb : Qb;
  const float* gvec = sel ? gk : gq;
  int t = threadIdx.x;
  u16* row = P + (size_t)l * DIMSZ;
  float xv[6];
  #pragma unroll
  for (int i = 0; i < 3; i++) {
    int p = i * 256 + t;
    ushort2 u = *(const ushort2*)(row + 2 * p);
    xv[2 * i] = b2f(u.x);
    xv[2 * i + 1] = b2f(u.y);
  }
  float ss = 0.f;
  #pragma unroll
  for (int i = 0; i < 6; i++) ss += xv[i] * xv[i];
  #pragma unroll
  for (int d = 32; d; d >>= 1) ss += __shfl_down(ss, d);
  __shared__ float red[4];
  __shared__ float rshare;
  if ((t & 63) == 0) red[t >> 6] = ss;
  __syncthreads();
  if (t == 0) rshare = rsqrtf((red[0] + red[1] + red[2] + red[3]) * (1.0f / DIMSZ) + 1e-6f);
  __syncthreads();
  float rms = rshare;

  const float* f = (l < 3584) ? (freqs + (size_t)l * HEADD)
                : (l < 3680) ? (freqs_a + (size_t)(l - 3584) * HEADD)
                             : (freqs_s + (size_t)(l - 3680) * HEADD);
  #pragma unroll
  for (int i = 0; i < 3; i++) {
    int p = i * 256 + t;
    int j = p & 63;
    float2 csn = *(const float2*)(f + 2 * j);
    float2 gv = *(const float2*)(gvec + 2 * p);
    float xr = xv[2 * i] * rms * gv.x;
    float xi = xv[2 * i + 1] * rms * gv.y;
    ushort2 o;
    o.x = f2b(xr * csn.x - xi * csn.y);
    o.y = f2b(xr * csn.y + xi * csn.x);
    *(ushort2*)(row + 2 * p) = o;
  }
}

// ---------------- fused attention: tail blocks (bx<84) + dense blocks ----------------
#define PSLOT_U16 16640   // 128*128 bf16 O + 128 f32 l
#define NTAIL 84
__launch_bounds__(256, 2)
__global__ void attn_fused_kernel(const u16* __restrict__ Q, const u16* __restrict__ K,
                                  const u16* __restrict__ Vt, u16* __restrict__ O,
                                  u16* __restrict__ DP, float* __restrict__ Part) {
  __shared__ __align__(16) u16 Ks[2][32 * 136];
  __shared__ __align__(16) u16 Vs[2][128 * 40];
  __shared__ __align__(16) u16 Pl[4][32 * 40];

  int t = threadIdx.x, lane = t & 63, w = t >> 6, g = lane >> 4, c = lane & 15;
  const float c1 = SM_SCALE * 1.44269504088896340f;
  const float c2 = 12.0f * 1.44269504088896340f;

  f32x4 zero = {0.f, 0.f, 0.f, 0.f};
  bf16x8 onesv;
  {
    u16 ob = 0x3F80;
    #pragma unroll
    for (int i = 0; i < 8; i++) onesv[i] = ((const __bf16*)&ob)[0];
  }

  if (blockIdx.x < NTAIL) {
    // ================= tail path (action+state rows), reg-pipeline =================
    char* smem = (char*)&Ks[0][0];          // 20608 B used, fits in 48128
    float* Lsum = (float*)(smem + 20608);   // 128 B

    int j = blockIdx.x;
    int bxx = j % 7;
    int h = j / 7;
    int qt, part;
    if (bxx < 3) { qt = 112 + bxx; part = 0; }
    else if (bxx < 6) { qt = 112 + (bxx - 3); part = 1; }
    else { qt = 115; part = 0; }
    int qbase = qt * 32;
    bool heavy = (qt <= 114);

    int S0, E0, S1, E1, S2, E2, S3, E3, niv;
    if (qbase < 3680) {
      int b = (qbase - 3584) >> 5;
      int ibe = 512 + (b + 1) * 1024;
      int kv = imax(512, ibe - 2048);
      S0 = 0; E0 = 512; S1 = kv; E1 = ibe;
      S2 = 3584 + 32 * b; E2 = S2 + 32; S3 = 3680 + b; E3 = S3 + 1; niv = 4;
    } else {
      S0 = 3680; E0 = 3683; S1 = S2 = S3 = 0; E1 = E2 = E3 = 0; niv = 1;
    }
    bool diag = (qbase >= 3680);

    int B0 = S0 & ~31, B1 = S1 & ~31, B2 = S2 & ~31, B3 = S3 & ~31;
    int T1 = (E0 - B0 + 31) >> 5;
    int T2 = T1 + ((niv > 1) ? ((E1 - B1 + 31) >> 5) : 0);
    int T3 = T2 + ((niv > 2) ? ((E2 - B2 + 31) >> 5) : 0);
    int T4 = T3 + ((niv > 3) ? ((E3 - B3 + 31) >> 5) : 0);
    int ntile = T4;

    int rlo = 0, rhi = ntile;
    if (heavy) { int half = (ntile + 1) >> 1; if (part == 0) rhi = half; else rlo = half; }

    auto tile_of = [&](int f, int& k0, int& lo, int& hi) {
      k0 = B0 + (f << 5); lo = S0; hi = E0;
      if (niv > 1 && f >= T1) { k0 = B1 + ((f - T1) << 5); lo = S1; hi = E1; }
      if (niv > 2 && f >= T2) { k0 = B2 + ((f - T2) << 5); lo = S2; hi = E2; }
      if (niv > 3 && f >= T3) { k0 = B3 + ((f - T3) << 5); lo = S3; hi = E3; }
    };

    bf16x8 qf[2][4];
    #pragma unroll
    for (int a = 0; a < 2; a++) {
      const u16* qp = Q + (size_t)(qbase + a * 16 + c) * DIMSZ + h * HEADD + 8 * g;
      #pragma unroll
      for (int s = 0; s < 4; s++) qf[a][s] = *(const bf16x8*)(qp + 32 * s);
    }

    f32x4 acc[2][8];
    f32x4 lacc[2];
    #pragma unroll
    for (int a = 0; a < 2; a++) {
      lacc[a] = zero;
      #pragma unroll
      for (int cc = 0; cc < 8; cc++) acc[a][cc] = zero;
    }

    u16* PwA = (u16*)smem + w * 2560;
    u16* PwB = PwA + 1280;

    bf16x8 kc[2][4], vbuf[8], pa0, pa1;

    auto loadK = [&](int k0) {
      #pragma unroll
      for (int k2 = 0; k2 < 2; k2++) {
        const u16* kp = K + (size_t)(k0 + 16 * k2 + c) * DIMSZ + h * HEADD + 8 * g;
        #pragma unroll
        for (int s = 0; s < 4; s++) kc[k2][s] = *(const bf16x8*)(kp + 32 * s);
      }
    };
    auto loadV = [&](int k0) {
      #pragma unroll
      for (int cc = 0; cc < 8; cc++)
        vbuf[cc] = *(const bf16x8*)(Vt + (size_t)(h * HEADD + cc * 16 + c) * LPAD + k0 + 8 * g);
    };
    auto QKf = [&](f32x4 (&sc)[2][2]) {
      sc[0][0] = zero; sc[0][1] = zero; sc[1][0] = zero; sc[1][1] = zero;
      #pragma unroll
      for (int k2 = 0; k2 < 2; k2++)
        #pragma unroll
        for (int s = 0; s < 4; s++) {
          sc[0][k2] = __builtin_amdgcn_mfma_f32_16x16x32_bf16(qf[0][s], kc[k2][s], sc[0][k2], 0, 0, 0);
          sc[1][k2] = __builtin_amdgcn_mfma_f32_16x16x32_bf16(qf[1][s], kc[k2][s], sc[1][k2], 0, 0, 0);
        }
    };
    auto smstore = [&](f32x4 (&sc)[2][2], int k0, int lo, int hi, u16* Pw) {
      #pragma unroll
      for (int a = 0; a < 2; a++)
        #pragma unroll
        for (int k2 = 0; k2 < 2; k2++) {
          int k = k0 + k2 * 16 + c;
          bool valid = (k >= lo) && (k < hi);
          #pragma unroll
          for (int r = 0; r < 4; r++) {
            float p = __builtin_amdgcn_exp2f(sc[a][k2][r] * c1 - c2);
            bool v = valid;
            if (diag) { int qr = qbase + a * 16 + 4 * g + r; v = v && (k == qr); }
            Pw[(a * 16 + 4 * g + r) * 40 + k2 * 16 + c] = v ? f2b(p) : (u16)0;
          }
        }
    };
    auto readP = [&](u16* Pw) {
      pa0 = *(const bf16x8*)&Pw[c * 40 + 8 * g];
      pa1 = *(const bf16x8*)&Pw[(16 + c) * 40 + 8 * g];
    };
    auto PV = [&]() {
      #pragma unroll
      for (int cc = 0; cc < 8; cc++) {
        acc[0][cc] = __builtin_amdgcn_mfma_f32_16x16x32_bf16(pa0, vbuf[cc], acc[0][cc], 0, 0, 0);
        acc[1][cc] = __builtin_amdgcn_mfma_f32_16x16x32_bf16(pa1, vbuf[cc], acc[1][cc], 0, 0, 0);
      }
      lacc[0] = __builtin_amdgcn_mfma_f32_16x16x32_bf16(pa0, onesv, lacc[0], 0, 0, 0);
      lacc[1] = __builtin_amdgcn_mfma_f32_16x16x32_bf16(pa1, onesv, lacc[1], 0, 0, 0);
    };

    int i = rlo + w;
    if (i < rhi) {
      int ik0, ilo, ihi; tile_of(i, ik0, ilo, ihi);
      loadK(ik0);
      loadV(ik0);
      {
        f32x4 sc[2][2]; QKf(sc);
        smstore(sc, ik0, ilo, ihi, PwA);
      }
      asm volatile("s_waitcnt lgkmcnt(0)" ::: "memory");
      __builtin_amdgcn_sched_barrier(0);
      readP(PwA);
      int nx = i + 4;
      int nk0 = 0, nlo = 0, nhi = 0;
      bool useB = true;
      if (nx < rhi) { tile_of(nx, nk0, nlo, nhi); loadK(nk0); }
      while (nx < rhi) {
        int ck0 = nk0, clo = nlo, chi = nhi;
        f32x4 sc[2][2]; QKf(sc);
        int nn = nx + 4;
        if (nn < rhi) { tile_of(nn, nk0, nlo, nhi); loadK(nk0); }
        u16* Pw = useB ? PwB : PwA;
        smstore(sc, ck0, clo, chi, Pw);
        PV();
        loadV(ck0);
        asm volatile("s_waitcnt lgkmcnt(0)" ::: "memory");
        __builtin_amdgcn_sched_barrier(0);
        readP(Pw);
        useB = !useB;
        i = nx; nx = nn;
      }
      PV();
    }

    __syncthreads();
    float* Oacc = (float*)smem;
    if (w == 0) {
      #pragma unroll
      for (int a = 0; a < 2; a++) {
        #pragma unroll
        for (int cc = 0; cc < 8; cc++)
          #pragma unroll
          for (int r = 0; r < 4; r++)
            Oacc[(a * 16 + 4 * g + r) * 132 + cc * 16 + c] = acc[a][cc][r];
        if (c == 0)
          #pragma unroll
          for (int r = 0; r < 4; r++) Lsum[a * 16 + 4 * g + r] = lacc[a][r];
      }
    }
    __syncthreads();
    #pragma unroll
    for (int ww = 1; ww < 4; ww++) {
      if (w == ww) {
        #pragma unroll
        for (int a = 0; a < 2; a++) {
          #pragma unroll
          for (int cc = 0; cc < 8; cc++)
            #pragma unroll
            for (int r = 0; r < 4; r++)
              Oacc[(a * 16 + 4 * g + r) * 132 + cc * 16 + c] += acc[a][cc][r];
          if (c == 0)
            #pragma unroll
            for (int r = 0; r < 4; r++) Lsum[a * 16 + 4 * g + r] += lacc[a][r];
        }
      }
      __syncthreads();
    }

    int row = t >> 3, c0 = (t & 7) * 16;
    if (heavy) {
      size_t slot = ((size_t)((qt - 112) * 12 + h)) * 2 + part;
      float* P = Part + slot * 4160;
      #pragma unroll
      for (int jj = 0; jj < 16; jj += 4)
        *(float4*)&P[row * 128 + c0 + jj] = *(float4*)&Oacc[row * 132 + c0 + jj];
      if ((t & 7) == 0) P[4096 + row] = Lsum[row];
    } else {
      int orow = qbase + row;
      if (orow < LSEQ) {
        float lsv = Lsum[row];
        float inv = (lsv > 0.f) ? 1.0f / lsv : 0.f;
        u16 tmp[16];
        #pragma unroll
        for (int jj = 0; jj < 16; jj++) tmp[jj] = f2b(Oacc[row * 132 + c0 + jj] * inv);
        u16* op = O + (size_t)orow * DIMSZ + h * HEADD + c0;
        *(uint4*)(op) = *(uint4*)&tmp[0];
        *(uint4*)(op + 8) = *(uint4*)&tmp[8];
      }
    }
    return;
  }

  // ================= dense path (staged shared-KV flash, R11-proven) =================
  int bx = blockIdx.x - NTAIL;
  int qbase, h, part, nparts, fb;
  if (bx < 48) { qbase = (bx / 12) * 128; h = bx % 12; part = 0; nparts = 1; fb = -1; }
  else if (bx < 336) { int i = bx - 48; int qb = i / 36; h = (i / 3) % 12; part = i % 3; nparts = 3; fb = 0; qbase = 512 + qb * 128; }
  else if (bx < 720) { int i = bx - 336; int qb = i / 48; h = (i / 4) % 12; part = i % 4; nparts = 4; fb = 1; qbase = 1536 + qb * 128; }
  else { int i = bx - 720; int qb = i / 48; h = (i / 4) % 12; part = i % 4; nparts = 4; fb = 2; qbase = 2560 + qb * 128; }

  int S0, E0, S1, E1, S2, E2, S3, E3, niv;
  if (fb < 0) { S0 = 0; E0 = 512; S1 = E1 = S2 = E2 = S3 = E3 = 0; niv = 1; }
  else {
    int be = 512 + (fb + 1) * 1024;
    int kv = imax(512, be - 2048);
    S0 = 0; E0 = 512; S1 = kv; E1 = be;
    S2 = 3584 + 32 * fb; E2 = S2 + 32; S3 = 3680 + fb; E3 = S3 + 1; niv = 4;
  }
  int B0 = S0 & ~31, B1 = S1 & ~31, B2 = S2 & ~31, B3 = S3 & ~31;
  int T1 = (E0 - B0 + 31) >> 5;
  int T2 = T1 + ((niv > 1) ? ((E1 - B1 + 31) >> 5) : 0);
  int T3 = T2 + ((niv > 2) ? ((E2 - B2 + 31) >> 5) : 0);
  int T4 = T3 + ((niv > 3) ? ((E3 - B3 + 31) >> 5) : 0);
  int ntile = T4;
  int rlo = (ntile * part) / nparts, rhi = (ntile * (part + 1)) / nparts;

  auto tile_of = [&](int f, int& k0, int& lo, int& hi) {
    k0 = B0 + (f << 5); lo = S0; hi = E0;
    if (niv > 1 && f >= T1) { k0 = B1 + ((f - T1) << 5); lo = S1; hi = E1; }
    if (niv > 2 && f >= T2) { k0 = B2 + ((f - T2) << 5); lo = S2; hi = E2; }
    if (niv > 3 && f >= T3) { k0 = B3 + ((f - T3) << 5); lo = S3; hi = E3; }
  };

  const u16* kgp = K + (size_t)(t >> 3) * DIMSZ + h * HEADD + 8 * (t & 7);
  int kds = (t >> 3) * 136 + 8 * (t & 7);
  const u16* vgp = Vt + ((size_t)h * HEADD + (t >> 1)) * LPAD + 16 * (t & 1);
  int vds = (t >> 1) * 40 + 16 * (t & 1);

  uint4 sk0, sk1, sv0, sv1;
  auto stage_load = [&](int k0) {
    const u16* kp = kgp + (size_t)k0 * DIMSZ;
    sk0 = *(const uint4*)(kp);
    sk1 = *(const uint4*)(kp + 64);
    sv0 = *(const uint4*)(vgp + k0);
    sv1 = *(const uint4*)(vgp + k0 + 8);
  };
  auto stage_write = [&](int buf) {
    *(uint4*)&Ks[buf][kds] = sk0;
    *(uint4*)&Ks[buf][kds + 64] = sk1;
    *(uint4*)&Vs[buf][vds] = sv0;
    *(uint4*)&Vs[buf][vds + 8] = sv1;
  };

  int qrow0 = qbase + 32 * w;
  bf16x8 qf[2][4];
  #pragma unroll
  for (int a = 0; a < 2; a++) {
    const u16* qp = Q + (size_t)(qrow0 + a * 16 + c) * DIMSZ + h * HEADD + 8 * g;
    #pragma unroll
    for (int s = 0; s < 4; s++) qf[a][s] = *(const bf16x8*)(qp + 32 * s);
  }

  f32x4 acc[2][8];
  f32x4 lacc[2];
  #pragma unroll
  for (int a = 0; a < 2; a++) {
    lacc[a] = zero;
    #pragma unroll
    for (int cc = 0; cc < 8; cc++) acc[a][cc] = zero;
  }

  u16* Pw = &Pl[w][0];
  __bf16* Pwh = (__bf16*)Pw;

  {
    int k0, lo, hi; tile_of(rlo, k0, lo, hi);
    stage_load(k0);
    stage_write(0);
  }
  __syncthreads();
  int cur = 0;

  for (int tt = rlo; tt < rhi; ++tt) {
    int ck0, clo, chi; tile_of(tt, ck0, clo, chi);
    bool pre = (tt + 1 < rhi);
    if (pre) { int nk0, nl, nh; tile_of(tt + 1, nk0, nl, nh); stage_load(nk0); }

    f32x4 sc[2][2];
    sc[0][0] = zero; sc[0][1] = zero; sc[1][0] = zero; sc[1][1] = zero;
    #pragma unroll
    for (int k2 = 0; k2 < 2; k2++)
      #pragma unroll
      for (int s = 0; s < 4; s++) {
        bf16x8 kf = *(const bf16x8*)&Ks[cur][(16 * k2 + c) * 136 + 32 * s + 8 * g];
        sc[0][k2] = __builtin_amdgcn_mfma_f32_16x16x32_bf16(qf[0][s], kf, sc[0][k2], 0, 0, 0);
        sc[1][k2] = __builtin_amdgcn_mfma_f32_16x16x32_bf16(qf[1][s], kf, sc[1][k2], 0, 0, 0);
      }

    if (ck0 >= clo && ck0 + 32 <= chi) {
      // interior tile: no masking, native bf16 cvt
      #pragma unroll
      for (int a = 0; a < 2; a++)
        #pragma unroll
        for (int k2 = 0; k2 < 2; k2++)
          #pragma unroll
          for (int r = 0; r < 4; r++) {
            float p = __builtin_amdgcn_exp2f(sc[a][k2][r] * c1 - c2);
            Pwh[(a * 16 + 4 * g + r) * 40 + k2 * 16 + c] = (__bf16)p;
          }
    } else {
      #pragma unroll
      for (int a = 0; a < 2; a++)
        #pragma unroll
        for (int k2 = 0; k2 < 2; k2++) {
          int k = ck0 + k2 * 16 + c;
          bool valid = (k >= clo) && (k < chi);
          #pragma unroll
          for (int r = 0; r < 4; r++) {
            float p = __builtin_amdgcn_exp2f(sc[a][k2][r] * c1 - c2);
            Pwh[(a * 16 + 4 * g + r) * 40 + k2 * 16 + c] = valid ? (__bf16)p : (__bf16)0.0f;
          }
        }
    }
    asm volatile("s_waitcnt lgkmcnt(0)" ::: "memory");
    __builtin_amdgcn_sched_barrier(0);

    bf16x8 pa0 = *(const bf16x8*)&Pw[c * 40 + 8 * g];
    bf16x8 pa1 = *(const bf16x8*)&Pw[(16 + c) * 40 + 8 * g];

    #pragma unroll
    for (int cc = 0; cc < 8; cc++) {
      bf16x8 vf = *(const bf16x8*)&Vs[cur][(cc * 16 + c) * 40 + 8 * g];
      acc[0][cc] = __builtin_amdgcn_mfma_f32_16x16x32_bf16(pa0, vf, acc[0][cc], 0, 0, 0);
      acc[1][cc] = __builtin_amdgcn_mfma_f32_16x16x32_bf16(pa1, vf, acc[1][cc], 0, 0, 0);
    }
    lacc[0] = __builtin_amdgcn_mfma_f32_16x16x32_bf16(pa0, onesv, lacc[0], 0, 0, 0);
    lacc[1] = __builtin_amdgcn_mfma_f32_16x16x32_bf16(pa1, onesv, lacc[1], 0, 0, 0);

    if (pre) stage_write(cur ^ 1);
    __syncthreads();
    cur ^= 1;
  }

  if (nparts == 1) {
    float inv[2][4];
    #pragma unroll
    for (int a = 0; a < 2; a++)
      #pragma unroll
      for (int r = 0; r < 4; r++) inv[a][r] = (lacc[a][r] > 0.f) ? 1.0f / lacc[a][r] : 0.f;
    #pragma unroll
    for (int a = 0; a < 2; a++)
      #pragma unroll
      for (int cc = 0; cc < 8; cc++)
        #pragma unroll
        for (int r = 0; r < 4; r++) {
          int row = qrow0 + a * 16 + 4 * g + r;
          O[(size_t)row * DIMSZ + h * HEADD + cc * 16 + c] = f2b(acc[a][cc][r] * inv[a][r]);
        }
  } else {
    int qb = (qbase - 512 - fb * 1024) >> 7;
    int sbase = (fb == 0) ? 0 : (fb == 1 ? 288 : 672);
    int slot = sbase + (qb * 12 + h) * nparts + part;
    u16* DPs = DP + (size_t)slot * PSLOT_U16;
    float* lout = (float*)(DPs + 16384);
    #pragma unroll
    for (int a = 0; a < 2; a++) {
      #pragma unroll
      for (int cc = 0; cc < 8; cc++)
        #pragma unroll
        for (int r = 0; r < 4; r++)
          DPs[(32 * w + a * 16 + 4 * g + r) * 128 + cc * 16 + c] = f2b(acc[a][cc][r]);
      if (c == 0)
        #pragma unroll
        for (int r = 0; r < 4; r++) lout[32 * w + a * 16 + 4 * g + r] = lacc[a][r];
    }
  }
}

// ---------------- fused merge: dense partials (bx<24) + tail partials ----------------
__launch_bounds__(256)
__global__ void attn_merge_kernel(const u16* __restrict__ DP, const float* __restrict__ Part,
                                  u16* __restrict__ O) {
  int bx = blockIdx.x, h = blockIdx.y;
  int T = threadIdx.x;
  if (bx < 24) {
    int qi = bx;
    int fb = qi >> 3, qb = qi & 7;
    int nparts = (fb == 0) ? 3 : 4;
    int sbase = (fb == 0) ? 0 : (fb == 1 ? 288 : 672);
    int slot0 = sbase + (qb * 12 + h) * nparts;
    int qbase = 512 + fb * 1024 + qb * 128;
    int row = T >> 1, c0 = 64 * (T & 1);

    float sum[64];
    #pragma unroll
    for (int j = 0; j < 64; j++) sum[j] = 0.f;
    float l = 0.f;
    for (int p = 0; p < nparts; p++) {
      const u16* S = DP + (size_t)(slot0 + p) * PSLOT_U16;
      l += ((const float*)(S + 16384))[row];
      #pragma unroll
      for (int j = 0; j < 64; j += 8) {
        uint4 v = *(const uint4*)&S[row * 128 + c0 + j];
        const u16* pv = (const u16*)&v;
        #pragma unroll
        for (int q = 0; q < 8; q++) sum[j + q] += b2f(pv[q]);
      }
    }
    float inv = (l > 0.f) ? 1.0f / l : 0.f;
    u16 tmp[64];
    #pragma unroll
    for (int j = 0; j < 64; j++) tmp[j] = f2b(sum[j] * inv);
    u16* op = O + (size_t)(qbase + row) * DIMSZ + h * HEADD + c0;
    #pragma unroll
    for (int j = 0; j < 64; j += 8) *(uint4*)(op + j) = *(uint4*)&tmp[j];
  } else {
    int b = bx - 24;
    const float* A = Part + ((size_t)(b * 12 + h)) * 2 * 4160;
    const float* B = A + 4160;
    int row = T >> 3, c0 = (T & 7) * 16;
    float l = A[4096 + row] + B[4096 + row];
    float inv = (l > 0.f) ? 1.0f / l : 0.f;
    int orow = 3584 + b * 32 + row;
    u16 tmp[16];
    #pragma unroll
    for (int jj = 0; jj < 16; jj += 4) {
      float4 va = *(const float4*)&A[row * 128 + c0 + jj];
      float4 vb = *(const float4*)&B[row * 128 + c0 + jj];
      tmp[jj + 0] = f2b((va.x + vb.x) * inv);
      tmp[jj + 1] = f2b((va.y + vb.y) * inv);
      tmp[jj + 2] = f2b((va.z + vb.z) * inv);
      tmp[jj + 3] = f2b((va.w + vb.w) * inv);
    }
    u16* op = O + (size_t)orow * DIMSZ + h * HEADD + c0;
    *(uint4*)(op) = *(uint4*)&tmp[0];
    *(uint4*)(op + 8) = *(uint4*)&tmp[8];
  }
}

// ---------------- launch ----------------
extern "C" void kernel_launch(void* const* d_in, const int* in_sizes, int n_in,
                              void* d_out, int out_size, void* d_ws, size_t ws_size,
                              hipStream_t stream) {
  (void)in_sizes; (void)n_in; (void)out_size; (void)ws_size;
  const float* x       = (const float*)d_in[0];
  const float* freqs   = (const float*)d_in[1];
  const float* freqs_a = (const float*)d_in[2];
  const float* freqs_s = (const float*)d_in[3];
  const float* Wq = (const float*)d_in[4];
  const float* bq = (const float*)d_in[5];
  const float* Wk = (const float*)d_in[6];
  const float* bk = (const float*)d_in[7];
  const float* Wv = (const float*)d_in[8];
  const float* bv = (const float*)d_in[9];
  const float* Wo = (const float*)d_in[10];
  const float* bo = (const float*)d_in[11];
  const float* gq = (const float*)d_in[12];
  const float* gk = (const float*)d_in[13];
  float* out = (float*)d_out;

  char* ws = (char*)d_ws;
  size_t off = 0;
  auto alloc = [&](size_t bytes) -> void* {
    void* p = ws + off;
    off += (bytes + 255) & ~(size_t)255;
    return p;
  };
  u16* xb   = (u16*)alloc((size_t)LPAD * DIMSZ * 2);
  u16* Wt   = (u16*)alloc((size_t)4 * DIMSZ * DIMSZ * 2);
  u16* Qb   = (u16*)alloc((size_t)LPAD * DIMSZ * 2);
  u16* Kb   = (u16*)alloc((size_t)LPAD * DIMSZ * 2);
  u16* Vt   = (u16*)alloc((size_t)DIMSZ * LPAD * 2);
  u16* Ob   = (u16*)alloc((size_t)LPAD * DIMSZ * 2);
  u16* DP   = (u16*)alloc((size_t)1056 * PSLOT_U16 * 2);
  float* PartT = (float*)alloc((size_t)3 * 12 * 2 * 4160 * 4);

  prep_kernel<<<dim3(CONV_BLOCKS + 9216), 256, 0, stream>>>(x, xb, Wq, Wk, Wv, Wo, Wt);

  gemm_qkv384_kernel<<<dim3(240), 512, 0, stream>>>(xb, Wt, bq, bk, bv, Qb, Kb, Vt);

  normrope_kernel<<<dim3(LSEQ, 2), 256, 0, stream>>>(Qb, Kb, gq, gk, freqs, freqs_a, freqs_s);

  attn_fused_kernel<<<dim3(NTAIL + 1104), 256, 0, stream>>>(Qb, Kb, Vt, Ob, DP, PartT);
  attn_merge_kernel<<<dim3(27, 12), 256, 0, stream>>>(DP, PartT, Ob);

  gemm_out192_kernel<<<dim3(160), 512, 0, stream>>>(Ob, Wt + 3 * (size_t)DIMSZ * DIMSZ, bo, out);
}

// Round 12
// 216.750 us; speedup vs baseline: 1.1842x; 1.0039x over previous
//
// R17: single change vs R16 (217.6us): dense attention blocks remapped
// head-major (92 blocks/head = 4 + 8x3 + 8x4 + 8x4) then bijectively
// XCD-chunked (1104 = 8*138 -> each XCD owns 1.5 heads' contiguous jobs,
// K/V working set 2.8MB <= 4MB L2; was: all 12 heads per XCD, 23MB).
// Targets measured FETCH_SIZE 72.5MB vs ~35MB ideal in the latency-bound
// attn kernel. DP slot addressing unchanged. Everything else identical.
#include <hip/hip_runtime.h>

#define LSEQ 3683
#define LPAD 3840
#define DIMSZ 1536
#define NHEAD 12
#define HEADD 128
#define SM_SCALE 0.088388347648318447f   // 1/sqrt(128)

typedef unsigned short u16;
typedef unsigned int u32;
typedef __bf16 bf16x8 __attribute__((ext_vector_type(8)));
typedef float f32x4 __attribute__((ext_vector_type(4)));

__device__ __forceinline__ u16 f2b(float f) {
  u32 u = __float_as_uint(f);
  u += 0x7FFFu + ((u >> 16) & 1u);   // RNE
  return (u16)(u >> 16);
}
__device__ __forceinline__ float b2f(u16 s) {
  return __uint_as_float(((u32)s) << 16);
}
__device__ __forceinline__ int imax(int a, int b) { return a > b ? a : b; }

// async global->LDS, 16B per lane; lds base must be wave-uniform.
__device__ __forceinline__ void gl_lds16(const u16* g, u16* l) {
  __builtin_amdgcn_global_load_lds((const __attribute__((address_space(1))) u32*)g,
                                   (__attribute__((address_space(3))) u32*)l,
                                   16, 0, 0);
}

// bijective XCD-chunk swizzle (m204): round-robin orig -> contiguous chunks.
__device__ __forceinline__ int xcd_swz(int orig, int nwg) {
  int q = nwg >> 3, r = nwg & 7;
  int x = orig & 7, l = orig >> 3;
  return (x < r ? x * (q + 1) : r * (q + 1) + (x - r) * q) + l;
}

// ---------------- fused prep: x f32->bf16 pad + W transposes ----------------
#define CONV_BLOCKS 5760   // (LPAD*DIMSZ/4)/256
__global__ void prep_kernel(const float* __restrict__ x, u16* __restrict__ xb,
                            const float* __restrict__ W0, const float* __restrict__ W1,
                            const float* __restrict__ W2, const float* __restrict__ W3,
                            u16* __restrict__ Wt) {
  __shared__ float tile[32][33];
  int bx = blockIdx.x;
  if (bx < CONV_BLOCKS) {
    long idx = (long)bx * blockDim.x + threadIdx.x;
    long base = idx * 4;
    if (base >= (long)LPAD * DIMSZ) return;
    float4 v;
    if (base < (long)LSEQ * DIMSZ) v = *(const float4*)(x + base);
    else v = make_float4(0.f, 0.f, 0.f, 0.f);
    ushort4 o;
    o.x = f2b(v.x); o.y = f2b(v.y); o.z = f2b(v.z); o.w = f2b(v.w);
    *(ushort4*)(xb + base) = o;
  } else {
    int i = bx - CONV_BLOCKS;
    int z = i / 2304;               // 48*48 per matrix
    int r = i % 2304;
    int bxx = r % 48, byy = r / 48;
    const float* W = (z == 0) ? W0 : (z == 1) ? W1 : (z == 2) ? W2 : W3;
    u16* dst = Wt + (size_t)z * DIMSZ * DIMSZ;
    int k0 = bxx * 32, n0 = byy * 32;
    int tx = threadIdx.x & 31, ty = threadIdx.x >> 5;
    #pragma unroll
    for (int q = 0; q < 4; q++) {
      int k = k0 + ty + q * 8;
      tile[ty + q * 8][tx] = W[(size_t)k * DIMSZ + n0 + tx];
    }
    __syncthreads();
    #pragma unroll
    for (int q = 0; q < 4; q++) {
      int n = n0 + ty + q * 8;
      dst[(size_t)n * DIMSZ + k0 + tx] = f2b(tile[tx][ty + q * 8]);
    }
  }
}

// ================== shared GEMM building blocks ==================
#define BAR() __builtin_amdgcn_s_barrier()
#define LGK0() asm volatile("s_waitcnt lgkmcnt(0)" ::: "memory")
#define LGK8() asm volatile("s_waitcnt lgkmcnt(8)" ::: "memory")
#define VMC9() asm volatile("s_waitcnt vmcnt(9)" ::: "memory")
#define VMC6() asm volatile("s_waitcnt vmcnt(6)" ::: "memory")
#define VMC3() asm volatile("s_waitcnt vmcnt(3)" ::: "memory")
#define VMC0() asm volatile("s_waitcnt vmcnt(0)" ::: "memory")
#define PRIO1() __builtin_amdgcn_s_setprio(1)
#define PRIO0() __builtin_amdgcn_s_setprio(0)

// one 64-row staging issue (512 threads x 16B = 64 rows of 128B)
#define STG_A(buf, q, kt) \
  gl_lds16(gA + (size_t)((q) * 64) * DIMSZ + (kt), &Asg[buf][((q) * 64 + w * 8) * 64]);
#define STG_B(buf, q, kt) \
  gl_lds16(gB + (size_t)((q) * 64) * DIMSZ + (kt), &Bsg[buf][((q) * 64 + w * 8) * 64]);

// ds-read register subtiles (swizzled offsets off0/off1); 6 ds_read_b128 each
#define LDA3(buf, mh) { \
  _Pragma("unroll") for (int mf = 0; mf < 3; mf++) { \
    int rb = (wm * 96 + (mh) * 48 + mf * 16) * 64; \
    Ar[mf * 2 + 0] = *(const bf16x8*)&Asg[buf][rb + off0]; \
    Ar[mf * 2 + 1] = *(const bf16x8*)&Asg[buf][rb + off1]; } }
#define LDB3(buf, nh) { \
  _Pragma("unroll") for (int nf = 0; nf < 3; nf++) { \
    int rb = (wn * 96 + (nh) * 48 + nf * 16) * 64; \
    Br[nh][nf * 2 + 0] = *(const bf16x8*)&Bsg[buf][rb + off0]; \
    Br[nh][nf * 2 + 1] = *(const bf16x8*)&Bsg[buf][rb + off1]; } }

// one C-quadrant (3x3 frags) x K=64: 18 MFMA (384-template)
#define MFMAQ3(mh, nh) { \
  _Pragma("unroll") for (int mf = 0; mf < 3; mf++) \
    _Pragma("unroll") for (int nf = 0; nf < 3; nf++) { \
      acc[(mh)*3+mf][(nh)*3+nf] = __builtin_amdgcn_mfma_f32_16x16x32_bf16(Ar[mf*2+0], Br[nh][nf*2+0], acc[(mh)*3+mf][(nh)*3+nf], 0, 0, 0); \
      acc[(mh)*3+mf][(nh)*3+nf] = __builtin_amdgcn_mfma_f32_16x16x32_bf16(Ar[mf*2+1], Br[nh][nf*2+1], acc[(mh)*3+mf][(nh)*3+nf], 0, 0, 0); } }

// ======== 384x192 8-phase body (used by gemm_qkv) ========
#define GEMM384_BODY() \
  STG_B(0, 0, 0) STG_B(0, 1, 0) STG_B(0, 2, 0) \
  STG_A(0, 0, 0) STG_A(0, 1, 0) STG_A(0, 2, 0) \
  STG_A(0, 3, 0) STG_A(0, 4, 0) STG_A(0, 5, 0) \
  STG_B(1, 0, 64) STG_B(1, 1, 64) STG_B(1, 2, 64) \
  STG_A(1, 0, 64) STG_A(1, 1, 64) STG_A(1, 2, 64) \
  STG_A(1, 3, 64) STG_A(1, 4, 64) STG_A(1, 5, 64) \
  VMC9(); \
  BAR(); \
  for (int i = 0; i < DIMSZ / 64 / 2 - 1; ++i) { \
    int kt2 = (2 * i + 2) * 64; \
    int kt3 = (2 * i + 3) * 64; \
    LDA3(0, 0) LDB3(0, 0) \
    LGK8(); BAR(); LGK0(); \
    PRIO1(); MFMAQ3(0, 0) PRIO0(); \
    BAR(); \
    LDB3(0, 1) \
    BAR(); LGK0(); \
    PRIO1(); MFMAQ3(0, 1) PRIO0(); \
    BAR(); \
    LDA3(0, 1) \
    STG_B(0, 0, kt2) STG_B(0, 1, kt2) STG_B(0, 2, kt2) \
    BAR(); LGK0(); \
    PRIO1(); MFMAQ3(1, 1) PRIO0(); \
    BAR(); \
    STG_A(0, 0, kt2) STG_A(0, 1, kt2) STG_A(0, 2, kt2) \
    VMC6(); BAR(); \
    PRIO1(); MFMAQ3(1, 0) PRIO0(); \
    BAR(); \
    LDA3(1, 0) LDB3(1, 0) \
    STG_A(0, 3, kt2) STG_A(0, 4, kt2) STG_A(0, 5, kt2) \
    LGK8(); BAR(); LGK0(); \
    PRIO1(); MFMAQ3(0, 0) PRIO0(); \
    BAR(); \
    LDB3(1, 1) \
    BAR(); LGK0(); \
    PRIO1(); MFMAQ3(0, 1) PRIO0(); \
    BAR(); \
    LDA3(1, 1) \
    STG_B(1, 0, kt3) STG_B(1, 1, kt3) STG_B(1, 2, kt3) \
    BAR(); LGK0(); \
    PRIO1(); MFMAQ3(1, 1) PRIO0(); \
    BAR(); \
    STG_A(1, 0, kt3) STG_A(1, 1, kt3) STG_A(1, 2, kt3) \
    STG_A(1, 3, kt3) STG_A(1, 4, kt3) STG_A(1, 5, kt3) \
    VMC9(); BAR(); \
    PRIO1(); MFMAQ3(1, 0) PRIO0(); \
    BAR(); \
  } \
  { \
    LDA3(0, 0) LDB3(0, 0) \
    LGK8(); BAR(); LGK0(); \
    PRIO1(); MFMAQ3(0, 0) PRIO0(); \
    BAR(); \
    LDB3(0, 1) \
    BAR(); LGK0(); \
    PRIO1(); MFMAQ3(0, 1) PRIO0(); \
    BAR(); \
    LDA3(0, 1) \
    BAR(); LGK0(); \
    PRIO1(); MFMAQ3(1, 1) PRIO0(); \
    BAR(); \
    VMC0(); BAR(); \
    PRIO1(); MFMAQ3(1, 0) PRIO0(); \
    BAR(); \
    LDA3(1, 0) LDB3(1, 0) \
    LGK8(); BAR(); LGK0(); \
    PRIO1(); MFMAQ3(0, 0) PRIO0(); \
    BAR(); \
    LDB3(1, 1) \
    BAR(); LGK0(); \
    PRIO1(); MFMAQ3(0, 1) PRIO0(); \
    BAR(); \
    LDA3(1, 1) \
    BAR(); LGK0(); \
    PRIO1(); MFMAQ3(1, 1) PRIO0(); \
    MFMAQ3(1, 0) \
  }

__launch_bounds__(512, 2)
__global__ void gemm_qkv384_kernel(const u16* __restrict__ A, const u16* __restrict__ Wt,
                                   const float* __restrict__ bq, const float* __restrict__ bk,
                                   const float* __restrict__ bv,
                                   u16* __restrict__ Qb, u16* __restrict__ Kb,
                                   u16* __restrict__ Vt) {
  __shared__ __align__(16) u16 Asg[2][384 * 64];
  __shared__ __align__(16) u16 Bsg[2][192 * 64];

  int wg = xcd_swz(blockIdx.x, 10 * 24);
  int nt = wg % 24;                    // 24 col tiles of 192 (8 per matrix)
  int m0 = (wg / 24) * 384;
  int which = nt >> 3;
  const float* bias = (which == 0) ? bq : (which == 1) ? bk : bv;

  int t = threadIdx.x;
  int lane = t & 63, w = t >> 6;       // 8 waves
  int c = lane & 15, g = lane >> 4;
  int wm = w >> 1, wn = w & 1;         // 4x2 wave grid; wave tile 96x96

  int srow = t >> 3;
  int schunk = ((t & 7) ^ (srow & 7)) * 8;
  const u16* gA = A + (size_t)(m0 + srow) * DIMSZ + schunk;
  const u16* gB = Wt + (size_t)(nt * 192 + srow) * DIMSZ + schunk;

  int off0 = c * 64 + ((g) ^ (c & 7)) * 8;
  int off1 = c * 64 + ((g + 4) ^ (c & 7)) * 8;

  f32x4 acc[6][6];
  f32x4 zero = {0.f, 0.f, 0.f, 0.f};
  #pragma unroll
  for (int am = 0; am < 6; am++)
    #pragma unroll
    for (int an = 0; an < 6; an++) acc[am][an] = zero;
  bf16x8 Ar[6];
  bf16x8 Br[2][6];

  GEMM384_BODY()

  // epilogue: bias add + write. Q/K row-major, V transposed (pack 4 rows).
  #pragma unroll
  for (int an = 0; an < 6; an++) {
    int ncol = (nt & 7) * 192 + wn * 96 + (an / 3) * 48 + (an % 3) * 16 + c;
    float bvv = bias[ncol];
    #pragma unroll
    for (int am = 0; am < 6; am++) {
      int rowb = m0 + wm * 96 + (am / 3) * 48 + (am % 3) * 16 + 4 * g;
      if (which == 2) {
        ushort4 pv;
        pv.x = f2b(acc[am][an][0] + bvv);
        pv.y = f2b(acc[am][an][1] + bvv);
        pv.z = f2b(acc[am][an][2] + bvv);
        pv.w = f2b(acc[am][an][3] + bvv);
        *(ushort4*)&Vt[(size_t)ncol * LPAD + rowb] = pv;
      } else {
        u16* P = (which == 1) ? Kb : Qb;
        #pragma unroll
        for (int r = 0; r < 4; r++)
          P[(size_t)(rowb + r) * DIMSZ + ncol] = f2b(acc[am][an][r] + bvv);
      }
    }
  }
}

// ======== 192x192 4-phase final GEMM: 160 blocks, single round ========
// B single 48-col group per wave (wn in 0..3); A reuses LDA3 (wm in 0..1).
#define LDB3S(buf) { \
  _Pragma("unroll") for (int nf = 0; nf < 3; nf++) { \
    int rb = (wn * 48 + nf * 16) * 64; \
    Br2[nf * 2 + 0] = *(const bf16x8*)&Bsg[buf][rb + off0]; \
    Br2[nf * 2 + 1] = *(const bf16x8*)&Bsg[buf][rb + off1]; } }

#define MFMAQ2(mh) { \
  _Pragma("unroll") for (int mf = 0; mf < 3; mf++) \
    _Pragma("unroll") for (int nf = 0; nf < 3; nf++) { \
      acc2[(mh)*3+mf][nf] = __builtin_amdgcn_mfma_f32_16x16x32_bf16(Ar[mf*2+0], Br2[nf*2+0], acc2[(mh)*3+mf][nf], 0, 0, 0); \
      acc2[(mh)*3+mf][nf] = __builtin_amdgcn_mfma_f32_16x16x32_bf16(Ar[mf*2+1], Br2[nf*2+1], acc2[(mh)*3+mf][nf], 0, 0, 0); } }

__launch_bounds__(512, 2)
__global__ void gemm_out192_kernel(const u16* __restrict__ A, const u16* __restrict__ Bt,
                                   const float* __restrict__ bias, float* __restrict__ outF) {
  __shared__ __align__(16) u16 Asg[2][192 * 64];
  __shared__ __align__(16) u16 Bsg[2][192 * 64];

  int wg = xcd_swz(blockIdx.x, 160);
  int nt = wg & 7;                     // 8 col tiles of 192
  int m0 = (wg >> 3) * 192;            // 20 row tiles of 192

  int t = threadIdx.x;
  int lane = t & 63, w = t >> 6;
  int c = lane & 15, g = lane >> 4;
  int wm = w >> 2, wn = w & 3;         // 2x4 wave grid; wave tile 96x48

  int srow = t >> 3;
  int schunk = ((t & 7) ^ (srow & 7)) * 8;
  const u16* gA = A + (size_t)(m0 + srow) * DIMSZ + schunk;
  const u16* gB = Bt + (size_t)(nt * 192 + srow) * DIMSZ + schunk;

  int off0 = c * 64 + ((g) ^ (c & 7)) * 8;
  int off1 = c * 64 + ((g + 4) ^ (c & 7)) * 8;

  f32x4 acc2[6][3];
  f32x4 zero = {0.f, 0.f, 0.f, 0.f};
  #pragma unroll
  for (int am = 0; am < 6; am++)
    #pragma unroll
    for (int an = 0; an < 3; an++) acc2[am][an] = zero;
  bf16x8 Ar[6];
  bf16x8 Br2[6];

  // prologue: tile0 full (B,A), tile1 B only; drain tile0 -> vmcnt(3)
  STG_B(0, 0, 0) STG_B(0, 1, 0) STG_B(0, 2, 0)
  STG_A(0, 0, 0) STG_A(0, 1, 0) STG_A(0, 2, 0)
  STG_B(1, 0, 64) STG_B(1, 1, 64) STG_B(1, 2, 64)
  VMC3();
  BAR();

  for (int i = 0; i < DIMSZ / 64 / 2 - 1; ++i) {
    int ktn1 = (2 * i + 1) * 64;
    int kt2  = (2 * i + 2) * 64;
    int kt3  = (2 * i + 3) * 64;
    // P1: read buf0 (A-mh0 + B), stage A(2i+1) -> Asg[1]
    LDA3(0, 0) LDB3S(0)
    STG_A(1, 0, ktn1) STG_A(1, 1, ktn1) STG_A(1, 2, ktn1)
    LGK8(); BAR(); LGK0();
    PRIO1(); MFMAQ2(0) PRIO0();
    BAR();
    // P2: read buf0 A-mh1, stage B(2i+2) -> Bsg[0]; drain tile 2i+1
    LDA3(0, 1)
    STG_B(0, 0, kt2) STG_B(0, 1, kt2) STG_B(0, 2, kt2)
    VMC3(); BAR(); LGK0();
    PRIO1(); MFMAQ2(1) PRIO0();
    BAR();
    // P3: read buf1 (A-mh0 + B), stage A(2i+2) -> Asg[0]
    LDA3(1, 0) LDB3S(1)
    STG_A(0, 0, kt2) STG_A(0, 1, kt2) STG_A(0, 2, kt2)
    LGK8(); BAR(); LGK0();
    PRIO1(); MFMAQ2(0) PRIO0();
    BAR();
    // P4: read buf1 A-mh1, stage B(2i+3) -> Bsg[1]; drain tile 2i+2
    LDA3(1, 1)
    STG_B(1, 0, kt3) STG_B(1, 1, kt3) STG_B(1, 2, kt3)
    VMC3(); BAR(); LGK0();
    PRIO1(); MFMAQ2(1) PRIO0();
    BAR();
  }

  // peel (tiles 22, 23): stage only A(23)@P1; drain all at P2
  {
    LDA3(0, 0) LDB3S(0)
    STG_A(1, 0, DIMSZ - 64) STG_A(1, 1, DIMSZ - 64) STG_A(1, 2, DIMSZ - 64)
    LGK8(); BAR(); LGK0();
    PRIO1(); MFMAQ2(0) PRIO0();
    BAR();
    LDA3(0, 1)
    VMC0(); BAR(); LGK0();
    PRIO1(); MFMAQ2(1) PRIO0();
    BAR();
    LDA3(1, 0) LDB3S(1)
    LGK8(); BAR(); LGK0();
    PRIO1(); MFMAQ2(0) PRIO0();
    BAR();
    LDA3(1, 1)
    LGK0();
    MFMAQ2(1)
  }

  #pragma unroll
  for (int an = 0; an < 3; an++) {
    int ncol = nt * 192 + wn * 48 + an * 16 + c;
    float bvv = bias[ncol];
    #pragma unroll
    for (int am = 0; am < 6; am++) {
      int rowb = m0 + wm * 96 + (am / 3) * 48 + (am % 3) * 16 + 4 * g;
      #pragma unroll
      for (int r = 0; r < 4; r++) {
        int row = rowb + r;
        if (row < LSEQ) outF[(size_t)row * DIMSZ + ncol] = acc2[am][an][r] + bvv;
      }
    }
  }
}

// ---------------- RMSNorm + RoPE, in place ----------------
__launch_bounds__(256)
__global__ void normrope_kernel(u16* __restrict__ Qb, u16* __restrict__ Kb,
                                const float* __restrict__ gq, const float* __restrict__ gk,
                                const float* __restrict__ freqs, const float* __restrict__ freqs_a,
                                const float* __restrict__ freqs_s) {
  int l = blockIdx.x;
  int sel = blockIdx.y;
  u16* P = sel ? Kb : Qb;
  const float* gvec = sel ? gk : gq;
  int t = threadIdx.x;
  u16* row = P + (size_t)l * DIMSZ;
  float xv[6];
  #pragma unroll
  for (int i = 0; i < 3; i++) {
    int p = i * 256 + t;
    ushort2 u = *(const ushort2*)(row + 2 * p);
    xv[2 * i] = b2f(u.x);
    xv[2 * i + 1] = b2f(u.y);
  }
  float ss = 0.f;
  #pragma unroll
  for (int i = 0; i < 6; i++) ss += xv[i] * xv[i];
  #pragma unroll
  for (int d = 32; d; d >>= 1) ss += __shfl_down(ss, d);
  __shared__ float red[4];
  __shared__ float rshare;
  if ((t & 63) == 0) red[t >> 6] = ss;
  __syncthreads();
  if (t == 0) rshare = rsqrtf((red[0] + red[1] + red[2] + red[3]) * (1.0f / DIMSZ) + 1e-6f);
  __syncthreads();
  float rms = rshare;

  const float* f = (l < 3584) ? (freqs + (size_t)l * HEADD)
                : (l < 3680) ? (freqs_a + (size_t)(l - 3584) * HEADD)
                             : (freqs_s + (size_t)(l - 3680) * HEADD);
  #pragma unroll
  for (int i = 0; i < 3; i++) {
    int p = i * 256 + t;
    int j = p & 63;
    float2 csn = *(const float2*)(f + 2 * j);
    float2 gv = *(const float2*)(gvec + 2 * p);
    float xr = xv[2 * i] * rms * gv.x;
    float xi = xv[2 * i + 1] * rms * gv.y;
    ushort2 o;
    o.x = f2b(xr * csn.x - xi * csn.y);
    o.y = f2b(xr * csn.y + xi * csn.x);
    *(ushort2*)(row + 2 * p) = o;
  }
}

// ---------------- fused attention: tail blocks (bx<84) + dense blocks ----------------
#define PSLOT_U16 16640   // 128*128 bf16 O + 128 f32 l
#define NTAIL 84
__launch_bounds__(256, 2)
__global__ void attn_fused_kernel(const u16* __restrict__ Q, const u16* __restrict__ K,
                                  const u16* __restrict__ Vt, u16* __restrict__ O,
                                  u16* __restrict__ DP, float* __restrict__ Part) {
  __shared__ __align__(16) u16 Ks[2][32 * 136];
  __shared__ __align__(16) u16 Vs[2][128 * 40];
  __shared__ __align__(16) u16 Pl[4][32 * 40];

  int t = threadIdx.x, lane = t & 63, w = t >> 6, g = lane >> 4, c = lane & 15;
  const float c1 = SM_SCALE * 1.44269504088896340f;
  const float c2 = 12.0f * 1.44269504088896340f;

  f32x4 zero = {0.f, 0.f, 0.f, 0.f};
  bf16x8 onesv;
  {
    u16 ob = 0x3F80;
    #pragma unroll
    for (int i = 0; i < 8; i++) onesv[i] = ((const __bf16*)&ob)[0];
  }

  if (blockIdx.x < NTAIL) {
    // ================= tail path (action+state rows), reg-pipeline =================
    char* smem = (char*)&Ks[0][0];          // 20608 B used, fits in 48128
    float* Lsum = (float*)(smem + 20608);   // 128 B

    int j = blockIdx.x;
    int bxx = j % 7;
    int h = j / 7;
    int qt, part;
    if (bxx < 3) { qt = 112 + bxx; part = 0; }
    else if (bxx < 6) { qt = 112 + (bxx - 3); part = 1; }
    else { qt = 115; part = 0; }
    int qbase = qt * 32;
    bool heavy = (qt <= 114);

    int S0, E0, S1, E1, S2, E2, S3, E3, niv;
    if (qbase < 3680) {
      int b = (qbase - 3584) >> 5;
      int ibe = 512 + (b + 1) * 1024;
      int kv = imax(512, ibe - 2048);
      S0 = 0; E0 = 512; S1 = kv; E1 = ibe;
      S2 = 3584 + 32 * b; E2 = S2 + 32; S3 = 3680 + b; E3 = S3 + 1; niv = 4;
    } else {
      S0 = 3680; E0 = 3683; S1 = S2 = S3 = 0; E1 = E2 = E3 = 0; niv = 1;
    }
    bool diag = (qbase >= 3680);

    int B0 = S0 & ~31, B1 = S1 & ~31, B2 = S2 & ~31, B3 = S3 & ~31;
    int T1 = (E0 - B0 + 31) >> 5;
    int T2 = T1 + ((niv > 1) ? ((E1 - B1 + 31) >> 5) : 0);
    int T3 = T2 + ((niv > 2) ? ((E2 - B2 + 31) >> 5) : 0);
    int T4 = T3 + ((niv > 3) ? ((E3 - B3 + 31) >> 5) : 0);
    int ntile = T4;

    int rlo = 0, rhi = ntile;
    if (heavy) { int half = (ntile + 1) >> 1; if (part == 0) rhi = half; else rlo = half; }

    auto tile_of = [&](int f, int& k0, int& lo, int& hi) {
      k0 = B0 + (f << 5); lo = S0; hi = E0;
      if (niv > 1 && f >= T1) { k0 = B1 + ((f - T1) << 5); lo = S1; hi = E1; }
      if (niv > 2 && f >= T2) { k0 = B2 + ((f - T2) << 5); lo = S2; hi = E2; }
      if (niv > 3 && f >= T3) { k0 = B3 + ((f - T3) << 5); lo = S3; hi = E3; }
    };

    bf16x8 qf[2][4];
    #pragma unroll
    for (int a = 0; a < 2; a++) {
      const u16* qp = Q + (size_t)(qbase + a * 16 + c) * DIMSZ + h * HEADD + 8 * g;
      #pragma unroll
      for (int s = 0; s < 4; s++) qf[a][s] = *(const bf16x8*)(qp + 32 * s);
    }

    f32x4 acc[2][8];
    f32x4 lacc[2];
    #pragma unroll
    for (int a = 0; a < 2; a++) {
      lacc[a] = zero;
      #pragma unroll
      for (int cc = 0; cc < 8; cc++) acc[a][cc] = zero;
    }

    u16* PwA = (u16*)smem + w * 2560;
    u16* PwB = PwA + 1280;

    bf16x8 kc[2][4], vbuf[8], pa0, pa1;

    auto loadK = [&](int k0) {
      #pragma unroll
      for (int k2 = 0; k2 < 2; k2++) {
        const u16* kp = K + (size_t)(k0 + 16 * k2 + c) * DIMSZ + h * HEADD + 8 * g;
        #pragma unroll
        for (int s = 0; s < 4; s++) kc[k2][s] = *(const bf16x8*)(kp + 32 * s);
      }
    };
    auto loadV = [&](int k0) {
      #pragma unroll
      for (int cc = 0; cc < 8; cc++)
        vbuf[cc] = *(const bf16x8*)(Vt + (size_t)(h * HEADD + cc * 16 + c) * LPAD + k0 + 8 * g);
    };
    auto QKf = [&](f32x4 (&sc)[2][2]) {
      sc[0][0] = zero; sc[0][1] = zero; sc[1][0] = zero; sc[1][1] = zero;
      #pragma unroll
      for (int k2 = 0; k2 < 2; k2++)
        #pragma unroll
        for (int s = 0; s < 4; s++) {
          sc[0][k2] = __builtin_amdgcn_mfma_f32_16x16x32_bf16(qf[0][s], kc[k2][s], sc[0][k2], 0, 0, 0);
          sc[1][k2] = __builtin_amdgcn_mfma_f32_16x16x32_bf16(qf[1][s], kc[k2][s], sc[1][k2], 0, 0, 0);
        }
    };
    auto smstore = [&](f32x4 (&sc)[2][2], int k0, int lo, int hi, u16* Pw) {
      #pragma unroll
      for (int a = 0; a < 2; a++)
        #pragma unroll
        for (int k2 = 0; k2 < 2; k2++) {
          int k = k0 + k2 * 16 + c;
          bool valid = (k >= lo) && (k < hi);
          #pragma unroll
          for (int r = 0; r < 4; r++) {
            float p = __builtin_amdgcn_exp2f(sc[a][k2][r] * c1 - c2);
            bool v = valid;
            if (diag) { int qr = qbase + a * 16 + 4 * g + r; v = v && (k == qr); }
            Pw[(a * 16 + 4 * g + r) * 40 + k2 * 16 + c] = v ? f2b(p) : (u16)0;
          }
        }
    };
    auto readP = [&](u16* Pw) {
      pa0 = *(const bf16x8*)&Pw[c * 40 + 8 * g];
      pa1 = *(const bf16x8*)&Pw[(16 + c) * 40 + 8 * g];
    };
    auto PV = [&]() {
      #pragma unroll
      for (int cc = 0; cc < 8; cc++) {
        acc[0][cc] = __builtin_amdgcn_mfma_f32_16x16x32_bf16(pa0, vbuf[cc], acc[0][cc], 0, 0, 0);
        acc[1][cc] = __builtin_amdgcn_mfma_f32_16x16x32_bf16(pa1, vbuf[cc], acc[1][cc], 0, 0, 0);
      }
      lacc[0] = __builtin_amdgcn_mfma_f32_16x16x32_bf16(pa0, onesv, lacc[0], 0, 0, 0);
      lacc[1] = __builtin_amdgcn_mfma_f32_16x16x32_bf16(pa1, onesv, lacc[1], 0, 0, 0);
    };

    int i = rlo + w;
    if (i < rhi) {
      int ik0, ilo, ihi; tile_of(i, ik0, ilo, ihi);
      loadK(ik0);
      loadV(ik0);
      {
        f32x4 sc[2][2]; QKf(sc);
        smstore(sc, ik0, ilo, ihi, PwA);
      }
      asm volatile("s_waitcnt lgkmcnt(0)" ::: "memory");
      __builtin_amdgcn_sched_barrier(0);
      readP(PwA);
      int nx = i + 4;
      int nk0 = 0, nlo = 0, nhi = 0;
      bool useB = true;
      if (nx < rhi) { tile_of(nx, nk0, nlo, nhi); loadK(nk0); }
      while (nx < rhi) {
        int ck0 = nk0, clo = nlo, chi = nhi;
        f32x4 sc[2][2]; QKf(sc);
        int nn = nx + 4;
        if (nn < rhi) { tile_of(nn, nk0, nlo, nhi); loadK(nk0); }
        u16* Pw = useB ? PwB : PwA;
        smstore(sc, ck0, clo, chi, Pw);
        PV();
        loadV(ck0);
        asm volatile("s_waitcnt lgkmcnt(0)" ::: "memory");
        __builtin_amdgcn_sched_barrier(0);
        readP(Pw);
        useB = !useB;
        i = nx; nx = nn;
      }
      PV();
    }

    __syncthreads();
    float* Oacc = (float*)smem;
    if (w == 0) {
      #pragma unroll
      for (int a = 0; a < 2; a++) {
        #pragma unroll
        for (int cc = 0; cc < 8; cc++)
          #pragma unroll
          for (int r = 0; r < 4; r++)
            Oacc[(a * 16 + 4 * g + r) * 132 + cc * 16 + c] = acc[a][cc][r];
        if (c == 0)
          #pragma unroll
          for (int r = 0; r < 4; r++) Lsum[a * 16 + 4 * g + r] = lacc[a][r];
      }
    }
    __syncthreads();
    #pragma unroll
    for (int ww = 1; ww < 4; ww++) {
      if (w == ww) {
        #pragma unroll
        for (int a = 0; a < 2; a++) {
          #pragma unroll
          for (int cc = 0; cc < 8; cc++)
            #pragma unroll
            for (int r = 0; r < 4; r++)
              Oacc[(a * 16 + 4 * g + r) * 132 + cc * 16 + c] += acc[a][cc][r];
          if (c == 0)
            #pragma unroll
            for (int r = 0; r < 4; r++) Lsum[a * 16 + 4 * g + r] += lacc[a][r];
        }
      }
      __syncthreads();
    }

    int row = t >> 3, c0 = (t & 7) * 16;
    if (heavy) {
      size_t slot = ((size_t)((qt - 112) * 12 + h)) * 2 + part;
      float* P = Part + slot * 4160;
      #pragma unroll
      for (int jj = 0; jj < 16; jj += 4)
        *(float4*)&P[row * 128 + c0 + jj] = *(float4*)&Oacc[row * 132 + c0 + jj];
      if ((t & 7) == 0) P[4096 + row] = Lsum[row];
    } else {
      int orow = qbase + row;
      if (orow < LSEQ) {
        float lsv = Lsum[row];
        float inv = (lsv > 0.f) ? 1.0f / lsv : 0.f;
        u16 tmp[16];
        #pragma unroll
        for (int jj = 0; jj < 16; jj++) tmp[jj] = f2b(Oacc[row * 132 + c0 + jj] * inv);
        u16* op = O + (size_t)orow * DIMSZ + h * HEADD + c0;
        *(uint4*)(op) = *(uint4*)&tmp[0];
        *(uint4*)(op + 8) = *(uint4*)&tmp[8];
      }
    }
    return;
  }

  // ============ dense path (staged shared-KV flash, R11-proven) ============
  // Head-major job index + bijective XCD chunking: 1104 = 8 * 138, so XCD x
  // owns jobs [x*138, (x+1)*138) = 1.5 heads' worth -> K/V L2-resident.
  int bx0 = blockIdx.x - NTAIL;
  int j = (bx0 & 7) * 138 + (bx0 >> 3);
  int h = j / 92;
  int u = j % 92;                      // 92 jobs per head: 4 + 24 + 32 + 32
  int qbase, part, nparts, fb;
  if (u < 4) { fb = -1; qbase = u * 128; part = 0; nparts = 1; }
  else if (u < 28) { int v = u - 4; fb = 0; qbase = 512 + (v / 3) * 128; part = v % 3; nparts = 3; }
  else if (u < 60) { int v = u - 28; fb = 1; qbase = 1536 + (v / 4) * 128; part = v % 4; nparts = 4; }
  else { int v = u - 60; fb = 2; qbase = 2560 + (v / 4) * 128; part = v % 4; nparts = 4; }

  int S0, E0, S1, E1, S2, E2, S3, E3, niv;
  if (fb < 0) { S0 = 0; E0 = 512; S1 = E1 = S2 = E2 = S3 = E3 = 0; niv = 1; }
  else {
    int be = 512 + (fb + 1) * 1024;
    int kv = imax(512, be - 2048);
    S0 = 0; E0 = 512; S1 = kv; E1 = be;
    S2 = 3584 + 32 * fb; E2 = S2 + 32; S3 = 3680 + fb; E3 = S3 + 1; niv = 4;
  }
  int B0 = S0 & ~31, B1 = S1 & ~31, B2 = S2 & ~31, B3 = S3 & ~31;
  int T1 = (E0 - B0 + 31) >> 5;
  int T2 = T1 + ((niv > 1) ? ((E1 - B1 + 31) >> 5) : 0);
  int T3 = T2 + ((niv > 2) ? ((E2 - B2 + 31) >> 5) : 0);
  int T4 = T3 + ((niv > 3) ? ((E3 - B3 + 31) >> 5) : 0);
  int ntile = T4;
  int rlo = (ntile * part) / nparts, rhi = (ntile * (part + 1)) / nparts;

  auto tile_of = [&](int f, int& k0, int& lo, int& hi) {
    k0 = B0 + (f << 5); lo = S0; hi = E0;
    if (niv > 1 && f >= T1) { k0 = B1 + ((f - T1) << 5); lo = S1; hi = E1; }
    if (niv > 2 && f >= T2) { k0 = B2 + ((f - T2) << 5); lo = S2; hi = E2; }
    if (niv > 3 && f >= T3) { k0 = B3 + ((f - T3) << 5); lo = S3; hi = E3; }
  };

  const u16* kgp = K + (size_t)(t >> 3) * DIMSZ + h * HEADD + 8 * (t & 7);
  int kds = (t >> 3) * 136 + 8 * (t & 7);
  const u16* vgp = Vt + ((size_t)h * HEADD + (t >> 1)) * LPAD + 16 * (t & 1);
  int vds = (t >> 1) * 40 + 16 * (t & 1);

  uint4 sk0, sk1, sv0, sv1;
  auto stage_load = [&](int k0) {
    const u16* kp = kgp + (size_t)k0 * DIMSZ;
    sk0 = *(const uint4*)(kp);
    sk1 = *(const uint4*)(kp + 64);
    sv0 = *(const uint4*)(vgp + k0);
    sv1 = *(const uint4*)(vgp + k0 + 8);
  };
  auto stage_write = [&](int buf) {
    *(uint4*)&Ks[buf][kds] = sk0;
    *(uint4*)&Ks[buf][kds + 64] = sk1;
    *(uint4*)&Vs[buf][vds] = sv0;
    *(uint4*)&Vs[buf][vds + 8] = sv1;
  };

  int qrow0 = qbase + 32 * w;
  bf16x8 qf[2][4];
  #pragma unroll
  for (int a = 0; a < 2; a++) {
    const u16* qp = Q + (size_t)(qrow0 + a * 16 + c) * DIMSZ + h * HEADD + 8 * g;
    #pragma unroll
    for (int s = 0; s < 4; s++) qf[a][s] = *(const bf16x8*)(qp + 32 * s);
  }

  f32x4 acc[2][8];
  f32x4 lacc[2];
  #pragma unroll
  for (int a = 0; a < 2; a++) {
    lacc[a] = zero;
    #pragma unroll
    for (int cc = 0; cc < 8; cc++) acc[a][cc] = zero;
  }

  u16* Pw = &Pl[w][0];
  __bf16* Pwh = (__bf16*)Pw;

  {
    int k0, lo, hi; tile_of(rlo, k0, lo, hi);
    stage_load(k0);
    stage_write(0);
  }
  __syncthreads();
  int cur = 0;

  for (int tt = rlo; tt < rhi; ++tt) {
    int ck0, clo, chi; tile_of(tt, ck0, clo, chi);
    bool pre = (tt + 1 < rhi);
    if (pre) { int nk0, nl, nh; tile_of(tt + 1, nk0, nl, nh); stage_load(nk0); }

    f32x4 sc[2][2];
    sc[0][0] = zero; sc[0][1] = zero; sc[1][0] = zero; sc[1][1] = zero;
    #pragma unroll
    for (int k2 = 0; k2 < 2; k2++)
      #pragma unroll
      for (int s = 0; s < 4; s++) {
        bf16x8 kf = *(const bf16x8*)&Ks[cur][(16 * k2 + c) * 136 + 32 * s + 8 * g];
        sc[0][k2] = __builtin_amdgcn_mfma_f32_16x16x32_bf16(qf[0][s], kf, sc[0][k2], 0, 0, 0);
        sc[1][k2] = __builtin_amdgcn_mfma_f32_16x16x32_bf16(qf[1][s], kf, sc[1][k2], 0, 0, 0);
      }

    if (ck0 >= clo && ck0 + 32 <= chi) {
      // interior tile: no masking, native bf16 cvt
      #pragma unroll
      for (int a = 0; a < 2; a++)
        #pragma unroll
        for (int k2 = 0; k2 < 2; k2++)
          #pragma unroll
          for (int r = 0; r < 4; r++) {
            float p = __builtin_amdgcn_exp2f(sc[a][k2][r] * c1 - c2);
            Pwh[(a * 16 + 4 * g + r) * 40 + k2 * 16 + c] = (__bf16)p;
          }
    } else {
      #pragma unroll
      for (int a = 0; a < 2; a++)
        #pragma unroll
        for (int k2 = 0; k2 < 2; k2++) {
          int k = ck0 + k2 * 16 + c;
          bool valid = (k >= clo) && (k < chi);
          #pragma unroll
          for (int r = 0; r < 4; r++) {
            float p = __builtin_amdgcn_exp2f(sc[a][k2][r] * c1 - c2);
            Pwh[(a * 16 + 4 * g + r) * 40 + k2 * 16 + c] = valid ? (__bf16)p : (__bf16)0.0f;
          }
        }
    }
    asm volatile("s_waitcnt lgkmcnt(0)" ::: "memory");
    __builtin_amdgcn_sched_barrier(0);

    bf16x8 pa0 = *(const bf16x8*)&Pw[c * 40 + 8 * g];
    bf16x8 pa1 = *(const bf16x8*)&Pw[(16 + c) * 40 + 8 * g];

    #pragma unroll
    for (int cc = 0; cc < 8; cc++) {
      bf16x8 vf = *(const bf16x8*)&Vs[cur][(cc * 16 + c) * 40 + 8 * g];
      acc[0][cc] = __builtin_amdgcn_mfma_f32_16x16x32_bf16(pa0, vf, acc[0][cc], 0, 0, 0);
      acc[1][cc] = __builtin_amdgcn_mfma_f32_16x16x32_bf16(pa1, vf, acc[1][cc], 0, 0, 0);
    }
    lacc[0] = __builtin_amdgcn_mfma_f32_16x16x32_bf16(pa0, onesv, lacc[0], 0, 0, 0);
    lacc[1] = __builtin_amdgcn_mfma_f32_16x16x32_bf16(pa1, onesv, lacc[1], 0, 0, 0);

    if (pre) stage_write(cur ^ 1);
    __syncthreads();
    cur ^= 1;
  }

  if (nparts == 1) {
    float inv[2][4];
    #pragma unroll
    for (int a = 0; a < 2; a++)
      #pragma unroll
      for (int r = 0; r < 4; r++) inv[a][r] = (lacc[a][r] > 0.f) ? 1.0f / lacc[a][r] : 0.f;
    #pragma unroll
    for (int a = 0; a < 2; a++)
      #pragma unroll
      for (int cc = 0; cc < 8; cc++)
        #pragma unroll
        for (int r = 0; r < 4; r++) {
          int row = qrow0 + a * 16 + 4 * g + r;
          O[(size_t)row * DIMSZ + h * HEADD + cc * 16 + c] = f2b(acc[a][cc][r] * inv[a][r]);
        }
  } else {
    int qb = (qbase - 512 - fb * 1024) >> 7;
    int sbase = (fb == 0) ? 0 : (fb == 1 ? 288 : 672);
    int slot = sbase + (qb * 12 + h) * nparts + part;
    u16* DPs = DP + (size_t)slot * PSLOT_U16;
    float* lout = (float*)(DPs + 16384);
    #pragma unroll
    for (int a = 0; a < 2; a++) {
      #pragma unroll
      for (int cc = 0; cc < 8; cc++)
        #pragma unroll
        for (int r = 0; r < 4; r++)
          DPs[(32 * w + a * 16 + 4 * g + r) * 128 + cc * 16 + c] = f2b(acc[a][cc][r]);
      if (c == 0)
        #pragma unroll
        for (int r = 0; r < 4; r++) lout[32 * w + a * 16 + 4 * g + r] = lacc[a][r];
    }
  }
}

// ---------------- fused merge: dense partials (bx<24) + tail partials ----------------
__launch_bounds__(256)
__global__ void attn_merge_kernel(const u16* __restrict__ DP, const float* __restrict__ Part,
                                  u16* __restrict__ O) {
  int bx = blockIdx.x, h = blockIdx.y;
  int T = threadIdx.x;
  if (bx < 24) {
    int qi = bx;
    int fb = qi >> 3, qb = qi & 7;
    int nparts = (fb == 0) ? 3 : 4;
    int sbase = (fb == 0) ? 0 : (fb == 1 ? 288 : 672);
    int slot0 = sbase + (qb * 12 + h) * nparts;
    int qbase = 512 + fb * 1024 + qb * 128;
    int row = T >> 1, c0 = 64 * (T & 1);

    float sum[64];
    #pragma unroll
    for (int j = 0; j < 64; j++) sum[j] = 0.f;
    float l = 0.f;
    for (int p = 0; p < nparts; p++) {
      const u16* S = DP + (size_t)(slot0 + p) * PSLOT_U16;
      l += ((const float*)(S + 16384))[row];
      #pragma unroll
      for (int j = 0; j < 64; j += 8) {
        uint4 v = *(const uint4*)&S[row * 128 + c0 + j];
        const u16* pv = (const u16*)&v;
        #pragma unroll
        for (int q = 0; q < 8; q++) sum[j + q] += b2f(pv[q]);
      }
    }
    float inv = (l > 0.f) ? 1.0f / l : 0.f;
    u16 tmp[64];
    #pragma unroll
    for (int j = 0; j < 64; j++) tmp[j] = f2b(sum[j] * inv);
    u16* op = O + (size_t)(qbase + row) * DIMSZ + h * HEADD + c0;
    #pragma unroll
    for (int j = 0; j < 64; j += 8) *(uint4*)(op + j) = *(uint4*)&tmp[j];
  } else {
    int b = bx - 24;
    const float* A = Part + ((size_t)(b * 12 + h)) * 2 * 4160;
    const float* B = A + 4160;
    int row = T >> 3, c0 = (T & 7) * 16;
    float l = A[4096 + row] + B[4096 + row];
    float inv = (l > 0.f) ? 1.0f / l : 0.f;
    int orow = 3584 + b * 32 + row;
    u16 tmp[16];
    #pragma unroll
    for (int jj = 0; jj < 16; jj += 4) {
      float4 va = *(const float4*)&A[row * 128 + c0 + jj];
      float4 vb = *(const float4*)&B[row * 128 + c0 + jj];
      tmp[jj + 0] = f2b((va.x + vb.x) * inv);
      tmp[jj + 1] = f2b((va.y + vb.y) * inv);
      tmp[jj + 2] = f2b((va.z + vb.z) * inv);
      tmp[jj + 3] = f2b((va.w + vb.w) * inv);
    }
    u16* op = O + (size_t)orow * DIMSZ + h * HEADD + c0;
    *(uint4*)(op) = *(uint4*)&tmp[0];
    *(uint4*)(op + 8) = *(uint4*)&tmp[8];
  }
}

// ---------------- launch ----------------
extern "C" void kernel_launch(void* const* d_in, const int* in_sizes, int n_in,
                              void* d_out, int out_size, void* d_ws, size_t ws_size,
                              hipStream_t stream) {
  (void)in_sizes; (void)n_in; (void)out_size; (void)ws_size;
  const float* x       = (const float*)d_in[0];
  const float* freqs   = (const float*)d_in[1];
  const float* freqs_a = (const float*)d_in[2];
  const float* freqs_s = (const float*)d_in[3];
  const float* Wq = (const float*)d_in[4];
  const float* bq = (const float*)d_in[5];
  const float* Wk = (const float*)d_in[6];
  const float* bk = (const float*)d_in[7];
  const float* Wv = (const float*)d_in[8];
  const float* bv = (const float*)d_in[9];
  const float* Wo = (const float*)d_in[10];
  const float* bo = (const float*)d_in[11];
  const float* gq = (const float*)d_in[12];
  const float* gk = (const float*)d_in[13];
  float* out = (float*)d_out;

  char* ws = (char*)d_ws;
  size_t off = 0;
  auto alloc = [&](size_t bytes) -> void* {
    void* p = ws + off;
    off += (bytes + 255) & ~(size_t)255;
    return p;
  };
  u16* xb   = (u16*)alloc((size_t)LPAD * DIMSZ * 2);
  u16* Wt   = (u16*)alloc((size_t)4 * DIMSZ * DIMSZ * 2);
  u16* Qb   = (u16*)alloc((size_t)LPAD * DIMSZ * 2);
  u16* Kb   = (u16*)alloc((size_t)LPAD * DIMSZ * 2);
  u16* Vt   = (u16*)alloc((size_t)DIMSZ * LPAD * 2);
  u16* Ob   = (u16*)alloc((size_t)LPAD * DIMSZ * 2);
  u16* DP   = (u16*)alloc((size_t)1056 * PSLOT_U16 * 2);
  float* PartT = (float*)alloc((size_t)3 * 12 * 2 * 4160 * 4);

  prep_kernel<<<dim3(CONV_BLOCKS + 9216), 256, 0, stream>>>(x, xb, Wq, Wk, Wv, Wo, Wt);

  gemm_qkv384_kernel<<<dim3(240), 512, 0, stream>>>(xb, Wt, bq, bk, bv, Qb, Kb, Vt);

  normrope_kernel<<<dim3(LSEQ, 2), 256, 0, stream>>>(Qb, Kb, gq, gk, freqs, freqs_a, freqs_s);

  attn_fused_kernel<<<dim3(NTAIL + 1104), 256, 0, stream>>>(Qb, Kb, Vt, Ob, DP, PartT);
  attn_merge_kernel<<<dim3(27, 12), 256, 0, stream>>>(DP, PartT, Ob);

  gemm_out192_kernel<<<dim3(160), 512, 0, stream>>>(Ob, Wt + 3 * (size_t)DIMSZ * DIMSZ, bo, out);
}